// Round 5
// baseline (17693.326 us; speedup 1.0000x reference)
//
#include <hip/hip_runtime.h>
#include <hip/hip_bf16.h>

#define H 512
#define TSTEPS 100
#define BATCH 512
#define KB 16          // 512 / 32 k-blocks
#define NBLK 256
#define NT 512

typedef __attribute__((ext_vector_type(8))) short bf16x8;
typedef __attribute__((ext_vector_type(8))) unsigned short u16x8;
typedef __attribute__((ext_vector_type(4))) float f32x4;
typedef unsigned short u16;

__device__ __forceinline__ float bf2f(u16 u) {
    union { unsigned int i; float f; } z; z.i = ((unsigned int)u) << 16; return z.f;
}
__device__ __forceinline__ u16 f2bf(float f) {
    union { float f; unsigned int u; } z; z.f = f;
    unsigned int r = (z.u + 0x7fffu + ((z.u >> 16) & 1u)) >> 16;
    return (u16)r;
}
__device__ __forceinline__ float sigmoidf_(float x) { return 1.0f / (1.0f + __expf(-x)); }
__device__ __forceinline__ float ftanh(float x) {
    x = fminf(15.0f, fmaxf(-15.0f, x));
    float e = __expf(2.0f * x);
    return (e - 1.0f) / (e + 1.0f);
}
__device__ __forceinline__ f32x4 MF(bf16x8 a, bf16x8 b, f32x4 c) {
    return __builtin_amdgcn_mfma_f32_16x16x32_bf16(a, b, c, 0, 0, 0);
}

// packed fragment index for [M x 512] bf16, 16x32 frags; A and B share it so
// k-mapping errors cancel in the contraction.
__device__ __forceinline__ size_t pidx(int m, int k) {
    int kb = k >> 5, kin = k & 31;
    int lane = (m & 15) + (((kin >> 2) & 3) << 4);
    int j = (kin & 3) + ((kin >> 4) << 2);
    return ((size_t)((m >> 4) * KB + kb) * 64 + lane) * 8 + j;
}

// ---------------- grid barrier ----------------
__device__ __forceinline__ void gbar(unsigned* bar) {
    __syncthreads();
    if (threadIdx.x == 0) {
        unsigned g = __hip_atomic_load(&bar[1], __ATOMIC_RELAXED, __HIP_MEMORY_SCOPE_AGENT);
        if (__hip_atomic_fetch_add(&bar[0], 1u, __ATOMIC_ACQ_REL, __HIP_MEMORY_SCOPE_AGENT) == NBLK - 1u) {
            __hip_atomic_store(&bar[0], 0u, __ATOMIC_RELAXED, __HIP_MEMORY_SCOPE_AGENT);
            __hip_atomic_fetch_add(&bar[1], 1u, __ATOMIC_ACQ_REL, __HIP_MEMORY_SCOPE_AGENT);
        } else {
            while (__hip_atomic_load(&bar[1], __ATOMIC_RELAXED, __HIP_MEMORY_SCOPE_AGENT) == g) {
                __builtin_amdgcn_s_sleep(1);
            }
            __threadfence();
        }
    }
    __syncthreads();
}

// ---------------- prep ----------------
__global__ void prep_kernel(const float* __restrict__ W_emb, const float* __restrict__ enc_Wih,
                            const float* __restrict__ enc_bih, const float* __restrict__ enc_bhh,
                            const float* __restrict__ dec_bih, const float* __restrict__ dec_bhh,
                            float* __restrict__ Wc, float* __restrict__ bc, float* __restrict__ db) {
    int g = blockIdx.x * blockDim.x + threadIdx.x;
    if (g >= 4 * H) return;
    float s0 = 0.f, s1 = 0.f;
    for (int j = 0; j < H; ++j) {
        float w = enc_Wih[(size_t)g * H + j];
        s0 += w * W_emb[j * 2 + 0];
        s1 += w * W_emb[j * 2 + 1];
    }
    Wc[g * 2 + 0] = s0; Wc[g * 2 + 1] = s1;
    bc[g] = enc_bih[g] + enc_bhh[g];
    db[g] = dec_bih[g] + dec_bhh[g];
}

__global__ void pack_w(const float* __restrict__ W, u16* __restrict__ hi, u16* __restrict__ lo,
                       int total) {
    int idx = blockIdx.x * 256 + threadIdx.x;
    if (idx >= total) return;
    int m = idx >> 9, k = idx & 511;
    float v = W[idx];
    u16 h16 = f2bf(v);
    u16 l16 = f2bf(v - bf2f(h16));
    size_t p = pidx(m, k);
    hi[p] = h16; lo[p] = l16;
}

__global__ void zero4(float* __restrict__ p, int n) {
    int i = blockIdx.x * blockDim.x + threadIdx.x;
    if (i < n) p[i] = 0.f;
}

// ---------------- persistent encoder (512 thr, Whh hi+lo in LDS) ----------------
// writes ench in batch-major [b][t][h]
__global__ __launch_bounds__(NT, 1) void persist_enc(
    const float* __restrict__ x, const float* __restrict__ Wc, const float* __restrict__ bc,
    const u16* __restrict__ WeH, const u16* __restrict__ WeL,
    float* __restrict__ cbuf, u16* __restrict__ hbuf,
    u16* __restrict__ ench, unsigned* __restrict__ bar) {
    extern __shared__ char smem[];
    u16* wlds = (u16*)smem;                    // [4 q][2 hl][16 kb][512] = 128 KB
    float* exch = (float*)(smem + 131072);     // [4 q][64 lb][16 col] = 16 KB
    const int tid = threadIdx.x;
    const int lane = tid & 63;
    const int w = tid >> 6;
    const int q = w & 3, jh = w >> 2;
    const int blk = blockIdx.x;
    const int mi = blk >> 5, nni = blk & 31;
    const size_t BHs = (size_t)BATCH * H;

    for (int c = 0; c < 8; ++c) {
        int cq = c >> 1, hl = c & 1;
        const u16x8* s8 = (const u16x8*)((hl ? WeL : WeH) + (size_t)((cq * 32 + nni) * KB) * 512);
        u16x8* d8 = (u16x8*)(wlds + c * 8192);
        for (int i = tid; i < 1024; i += NT) d8[i] = s8[i];
    }
    __syncthreads();

    for (int t = 0; t < TSTEPS; ++t) {
        const u16* Ah = hbuf + (size_t)(t & 1) * 2 * BHs;
        const u16* Al = Ah + BHs;
        u16* Hh = hbuf + (size_t)((t + 1) & 1) * 2 * BHs;
        u16* Hl = Hh + BHs;
        f32x4 acc[2] = {};
#pragma unroll 4
        for (int kb = 0; kb < KB; ++kb) {
            bf16x8 bh = *(const bf16x8*)&wlds[((q * 2 + 0) * KB + kb) * 512 + lane * 8];
            bf16x8 bl = *(const bf16x8*)&wlds[((q * 2 + 1) * KB + kb) * 512 + lane * 8];
#pragma unroll
            for (int jj = 0; jj < 2; ++jj) {
                int j = jh * 2 + jj;
                size_t ab = ((size_t)((mi * 4 + j) * KB + kb) * 64 + lane) * 8;
                bf16x8 ah = *(const bf16x8*)&Ah[ab];
                bf16x8 al = *(const bf16x8*)&Al[ab];
                acc[jj] = MF(ah, bh, acc[jj]);
                acc[jj] = MF(ah, bl, acc[jj]);
                acc[jj] = MF(al, bh, acc[jj]);
            }
        }
        const int col = lane & 15, rg = lane >> 4;
#pragma unroll
        for (int jj = 0; jj < 2; ++jj)
#pragma unroll
            for (int r = 0; r < 4; ++r)
                exch[(q * 64 + (jh * 2 + jj) * 16 + rg * 4 + r) * 16 + col] = acc[jj][r];
        __syncthreads();
#pragma unroll
        for (int k = 0; k < 2; ++k) {
            int cell = k * NT + tid;
            int lb = cell >> 4, cl = cell & 15;
            int b = mi * 64 + lb, n = nni * 16 + cl;
            float x0 = x[((size_t)b * TSTEPS + t) * 2 + 0];
            float x1 = x[((size_t)b * TSTEPS + t) * 2 + 1];
            float g[4];
#pragma unroll
            for (int qq = 0; qq < 4; ++qq)
                g[qq] = exch[(qq * 64 + lb) * 16 + cl] + bc[qq * H + n]
                      + x0 * Wc[(qq * H + n) * 2 + 0] + x1 * Wc[(qq * H + n) * 2 + 1];
            size_t ci = (size_t)b * H + n;
            float cn = sigmoidf_(g[1]) * cbuf[ci] + sigmoidf_(g[0]) * ftanh(g[2]);
            float hn = sigmoidf_(g[3]) * ftanh(cn);
            cbuf[ci] = cn;
            u16 hh = f2bf(hn), hl16 = f2bf(hn - bf2f(hh));
            size_t p = pidx(b, n);
            Hh[p] = hh; Hl[p] = hl16;
            ench[((size_t)b * TSTEPS + t) * H + n] = hh;   // batch-major
        }
        gbar(bar);
    }
}

// ---------------- persistent decoder (512 thr): lstm -> bar -> [u2+attn] -> bar ----
__global__ __launch_bounds__(NT, 1) void persist_dec(
    const u16* __restrict__ WdiH, const u16* __restrict__ WdiL,
    const u16* __restrict__ WdhH, const u16* __restrict__ WdhL,
    const float* __restrict__ db,
    const u16* __restrict__ WqH, const u16* __restrict__ WqL,
    const u16* __restrict__ u1r, const u16* __restrict__ ench, const float* __restrict__ vv,
    float* __restrict__ cbuf, u16* __restrict__ hbuf,
    u16* __restrict__ dhi, u16* __restrict__ dlo,
    unsigned* __restrict__ bar) {
    extern __shared__ char smem[];
    u16* wlds = (u16*)smem;                    // [2 mat][4 q][16 kb][512] hi = 128 KB
    char* scratch = smem + 131072;             // 22.5 KB overlay region
    float* exch  = (float*)scratch;            // phase A: [4][64][16] = 16 KB
    float* u2row = (float*)scratch;            // phase C: [2][512] = 4 KB
    float* ssc   = (float*)(scratch + 4096);   // [2][100] scores
    float* ssm   = (float*)(scratch + 4928);   // [2][100] softmax
    f32x4* dacc  = (f32x4*)(scratch + 5760);   // [4 par][2 r][64 l][2] f32x4 = 16 KB
    const int tid = threadIdx.x;
    const int lane = tid & 63;
    const int w = tid >> 6;
    const int blk = blockIdx.x;
    const int mi = blk >> 5, nni = blk & 31;   // same-XCD blocks share nni -> lo-weights L2-resident
    const size_t BHs = (size_t)BATCH * H;

    float vvr[8];
    {
        float4 v0 = *(const float4*)&vv[lane * 8];
        float4 v1 = *(const float4*)&vv[lane * 8 + 4];
        vvr[0] = v0.x; vvr[1] = v0.y; vvr[2] = v0.z; vvr[3] = v0.w;
        vvr[4] = v1.x; vvr[5] = v1.y; vvr[6] = v1.z; vvr[7] = v1.w;
    }

    for (int c = 0; c < 8; ++c) {
        int mat = c >> 2, cq = c & 3;
        const u16x8* s8 = (const u16x8*)((mat ? WdhH : WdiH) + (size_t)((cq * 32 + nni) * KB) * 512);
        u16x8* d8 = (u16x8*)(wlds + c * 8192);
        for (int i = tid; i < 1024; i += NT) d8[i] = s8[i];
    }
    __syncthreads();

    for (int s = 0; s < TSTEPS; ++s) {
        // ---- phase A: LSTM gates + cell update ----
        {
            const u16* hAh = hbuf + (size_t)(s & 1) * 2 * BHs;
            const u16* hAl = hAh + BHs;
            u16* Hh = hbuf + (size_t)((s + 1) & 1) * 2 * BHs;
            u16* Hl = Hh + BHs;
            const int q = w & 3, jh = w >> 2;
            f32x4 acc[2] = {};
#pragma unroll
            for (int ph = 0; ph < 2; ++ph) {
                const u16* Ah = ph ? hAh : dhi;
                const u16* Al = ph ? hAl : dlo;
                const u16* Wl = ph ? WdhL : WdiL;
#pragma unroll 4
                for (int kb = 0; kb < KB; ++kb) {
                    bf16x8 bh = *(const bf16x8*)&wlds[((ph * 4 + q) * KB + kb) * 512 + lane * 8];
                    bf16x8 bl = *(const bf16x8*)&Wl[((size_t)((q * 32 + nni) * KB + kb) * 64 + lane) * 8];
#pragma unroll
                    for (int jj = 0; jj < 2; ++jj) {
                        int j = jh * 2 + jj;
                        size_t ab = ((size_t)((mi * 4 + j) * KB + kb) * 64 + lane) * 8;
                        bf16x8 ah = *(const bf16x8*)&Ah[ab];
                        bf16x8 al = *(const bf16x8*)&Al[ab];
                        acc[jj] = MF(ah, bh, acc[jj]);
                        acc[jj] = MF(ah, bl, acc[jj]);
                        acc[jj] = MF(al, bh, acc[jj]);
                    }
                }
            }
            const int col = lane & 15, rg = lane >> 4;
#pragma unroll
            for (int jj = 0; jj < 2; ++jj)
#pragma unroll
                for (int r = 0; r < 4; ++r)
                    exch[(q * 64 + (jh * 2 + jj) * 16 + rg * 4 + r) * 16 + col] = acc[jj][r];
            __syncthreads();
#pragma unroll
            for (int k = 0; k < 2; ++k) {
                int cell = k * NT + tid;
                int lb = cell >> 4, cl = cell & 15;
                int b = mi * 64 + lb, n = nni * 16 + cl;
                float g[4];
#pragma unroll
                for (int qq = 0; qq < 4; ++qq)
                    g[qq] = exch[(qq * 64 + lb) * 16 + cl] + db[qq * H + n];
                size_t ci = (size_t)b * H + n;
                float cn = sigmoidf_(g[1]) * cbuf[ci] + sigmoidf_(g[0]) * ftanh(g[2]);
                float hn = sigmoidf_(g[3]) * ftanh(cn);
                cbuf[ci] = cn;
                u16 hh = f2bf(hn), hl16 = f2bf(hn - bf2f(hh));
                size_t p = pidx(b, n);
                Hh[p] = hh; Hl[p] = hl16;
            }
        }
        if (s == TSTEPS - 1) break;
        gbar(bar);

        // ---- phase C: u2 (own 2 rows) + attention ----
        {
            const u16* Ah = hbuf + (size_t)((s + 1) & 1) * 2 * BHs;
            const u16* Al = Ah + BHs;
            const int mf = blk >> 3;
            f32x4 acc[4] = {};
#pragma unroll 4
            for (int kb = 0; kb < KB; ++kb) {
                size_t ab = ((size_t)(mf * KB + kb) * 64 + lane) * 8;
                bf16x8 ah = *(const bf16x8*)&Ah[ab];
                bf16x8 al = *(const bf16x8*)&Al[ab];
#pragma unroll
                for (int f = 0; f < 4; ++f) {
                    int n16 = w * 4 + f;
                    size_t fb = ((size_t)(n16 * KB + kb) * 64 + lane) * 8;
                    bf16x8 bh = *(const bf16x8*)&WqH[fb];
                    bf16x8 bl = *(const bf16x8*)&WqL[fb];
                    acc[f] = MF(ah, bh, acc[f]);
                    acc[f] = MF(ah, bl, acc[f]);
                    acc[f] = MF(al, bh, acc[f]);
                }
            }
            const int col = lane & 15, rg = lane >> 4;
            const int t0 = (blk & 7) * 2;
#pragma unroll
            for (int f = 0; f < 4; ++f)
#pragma unroll
                for (int r = 0; r < 4; ++r) {
                    int m = rg * 4 + r;
                    int n = (w * 4 + f) * 16 + col;
                    if (m == t0)     u2row[n] = acc[f][r];
                    if (m == t0 + 1) u2row[512 + n] = acc[f][r];
                }
        }
        __syncthreads();
        {
            const int r = tid >> 8;          // 0..1
            const int par = (tid >> 6) & 3;  // contiguous 25-cc range per wave
            const int ccb = par * 25;
            const int b = blk * 2 + r;
            float u2v[8];
            {
                float4 a0 = *(const float4*)&u2row[r * 512 + lane * 8];
                float4 a1 = *(const float4*)&u2row[r * 512 + lane * 8 + 4];
                u2v[0] = a0.x; u2v[1] = a0.y; u2v[2] = a0.z; u2v[3] = a0.w;
                u2v[4] = a1.x; u2v[5] = a1.y; u2v[6] = a1.z; u2v[7] = a1.w;
            }
            const u16* u1base = &u1r[(size_t)b * TSTEPS * H + lane * 8];
            const u16* ehbase = &ench[(size_t)b * TSTEPS * H + lane * 8];
            // scores: contiguous cc, 5-deep nontemporal load batches
            for (int i0 = 0; i0 < 25; i0 += 5) {
                u16x8 uvv[5];
#pragma unroll
                for (int u = 0; u < 5; ++u)
                    uvv[u] = __builtin_nontemporal_load((const u16x8*)&u1base[(size_t)(ccb + i0 + u) * H]);
#pragma unroll
                for (int u = 0; u < 5; ++u) {
                    float pp = 0.f;
#pragma unroll
                    for (int j = 0; j < 8; ++j)
                        pp += vvr[j] * ftanh(bf2f(uvv[u][j]) + u2v[j]);
#pragma unroll
                    for (int off = 32; off; off >>= 1) pp += __shfl_xor(pp, off);
                    if (lane == 0) ssc[r * 100 + ccb + i0 + u] = pp;
                }
            }
            __syncthreads();
            if (tid < 128) {
                int r2 = tid >> 6, ln = tid & 63;
                float s1 = ssc[r2 * 100 + ln];
                float s2 = (ln + 64 < 100) ? ssc[r2 * 100 + ln + 64] : -1e30f;
                float m = fmaxf(s1, s2);
#pragma unroll
                for (int off = 32; off; off >>= 1) m = fmaxf(m, __shfl_xor(m, off));
                float e1 = __expf(s1 - m);
                float e2 = (ln + 64 < 100) ? __expf(s2 - m) : 0.f;
                float sum = e1 + e2;
#pragma unroll
                for (int off = 32; off; off >>= 1) sum += __shfl_xor(sum, off);
                float inv = 1.f / sum;
                ssm[r2 * 100 + ln] = e1 * inv;
                if (ln + 64 < 100) ssm[r2 * 100 + ln + 64] = e2 * inv;
            }
            __syncthreads();
            // glimpse (same contiguous cc range)
            float ga[8] = {};
            for (int i0 = 0; i0 < 25; i0 += 5) {
                u16x8 evv[5];
#pragma unroll
                for (int u = 0; u < 5; ++u)
                    evv[u] = __builtin_nontemporal_load((const u16x8*)&ehbase[(size_t)(ccb + i0 + u) * H]);
#pragma unroll
                for (int u = 0; u < 5; ++u) {
                    float a = ssm[r * 100 + ccb + i0 + u];
#pragma unroll
                    for (int j = 0; j < 8; ++j) ga[j] += a * bf2f(evv[u][j]);
                }
            }
            f32x4 g0 = {ga[0], ga[1], ga[2], ga[3]};
            f32x4 g1 = {ga[4], ga[5], ga[6], ga[7]};
            dacc[(((par * 2 + r) * 64) + lane) * 2 + 0] = g0;
            dacc[(((par * 2 + r) * 64) + lane) * 2 + 1] = g1;
            __syncthreads();
            if (tid < 128) {
                int r2 = tid >> 6, l = tid & 63;
                float fin[8];
#pragma unroll
                for (int j = 0; j < 8; ++j) fin[j] = 0.f;
#pragma unroll
                for (int pq = 0; pq < 4; ++pq) {
                    f32x4 d0 = dacc[(((pq * 2 + r2) * 64) + l) * 2 + 0];
                    f32x4 d1 = dacc[(((pq * 2 + r2) * 64) + l) * 2 + 1];
                    fin[0] += d0[0]; fin[1] += d0[1]; fin[2] += d0[2]; fin[3] += d0[3];
                    fin[4] += d1[0]; fin[5] += d1[1]; fin[6] += d1[2]; fin[7] += d1[3];
                }
                int b2 = blk * 2 + r2;
                int h0 = l * 8;
#pragma unroll
                for (int qd = 0; qd < 2; ++qd) {
                    int k = h0 + 4 * qd;
                    size_t p = (((size_t)(b2 >> 4) * KB + (k >> 5)) * 64 + (b2 & 15)
                                + (((k >> 2) & 3) << 4)) * 8 + (((k >> 4) & 1) << 2);
                    float f0 = fin[4 * qd], f1 = fin[4 * qd + 1], f2 = fin[4 * qd + 2], f3 = fin[4 * qd + 3];
                    u16 a0 = f2bf(f0), a1 = f2bf(f1), a2 = f2bf(f2), a3 = f2bf(f3);
                    *(ushort4*)&dhi[p] = make_ushort4(a0, a1, a2, a3);
                    u16 c0 = f2bf(f0 - bf2f(a0)), c1 = f2bf(f1 - bf2f(a1));
                    u16 c2 = f2bf(f2 - bf2f(a2)), c3 = f2bf(f3 - bf2f(a3));
                    *(ushort4*)&dlo[p] = make_ushort4(c0, c1, c2, c3);
                }
            }
        }
        gbar(bar);
    }
}

// ---------------- u1 = ench @ W_ref.T (one-shot; rows are b*TSTEPS+cc) ----------------
__global__ __launch_bounds__(256) void gemm_u1(const u16* __restrict__ ench_row,
                                               const u16* __restrict__ Bh, const u16* __restrict__ Bl,
                                               u16* __restrict__ u1_row) {
    __shared__ u16 lds[2 * KB * 64 * 8];   // 32 KB
    const int tid = threadIdx.x;
    const int m0 = blockIdx.x * 32;
    {
        int r = tid >> 3;
        int o = tid & 7;
#pragma unroll
        for (int p8 = 0; p8 < 8; ++p8) {
            int k0 = (o + 8 * p8) * 8;
            const u16* src = &ench_row[(size_t)(m0 + r) * H + k0];
            ushort4 v0 = *(const ushort4*)&src[0];
            ushort4 v1 = *(const ushort4*)&src[4];
            int kb = k0 >> 5, kin0 = k0 & 31;
            int g0 = (kin0 >> 2) & 3;
            int jo = (kin0 >> 4) << 2;
            u16* base = &lds[(size_t)(((r >> 4) * KB + kb) * 64) * 8];
            *(ushort4*)&base[((r & 15) + 16 * g0) * 8 + jo] = v0;
            *(ushort4*)&base[((r & 15) + 16 * (g0 + 1)) * 8 + jo] = v1;
        }
    }
    __syncthreads();
    const int lane = tid & 63;
    const int w = tid >> 6;
    const int mw = w & 1, nh = w >> 1;
    for (int nc = 0; nc < 16; ++nc) {
        int n16 = nh * 16 + nc;
        f32x4 acc = {};
#pragma unroll 4
        for (int kb = 0; kb < KB; ++kb) {
            bf16x8 a = *(const bf16x8*)&lds[((mw * KB + kb) * 64 + lane) * 8];
            size_t fb = ((size_t)(n16 * KB + kb) * 64 + lane) * 8;
            bf16x8 bh = *(const bf16x8*)&Bh[fb];
            bf16x8 bl = *(const bf16x8*)&Bl[fb];
            acc = MF(a, bh, acc);
            acc = MF(a, bl, acc);
        }
        const int col = lane & 15, rg = lane >> 4;
#pragma unroll
        for (int r = 0; r < 4; ++r) {
            size_t mrow = (size_t)m0 + mw * 16 + rg * 4 + r;
            u1_row[mrow * H + n16 * 16 + col] = f2bf(acc[r]);
        }
    }
}

// ---------------- final ----------------
__global__ __launch_bounds__(256) void final_kernel(const u16* __restrict__ hi,
                                                    const u16* __restrict__ lo,
                                                    const float* __restrict__ fc1,
                                                    const float* __restrict__ fc2,
                                                    float* __restrict__ out) {
    const int b = blockIdx.x;
    __shared__ float hsh[H];
    __shared__ float red[256];
    for (int i = threadIdx.x; i < H; i += 256) {
        size_t p = pidx(b, i);
        hsh[i] = bf2f(hi[p]) + bf2f(lo[p]);
    }
    __syncthreads();
    float total = 0.f;
    for (int n = threadIdx.x; n < H; n += 256) {
        float acc = 0.f;
        for (int j = 0; j < H; ++j) acc += fc1[(size_t)n * H + j] * hsh[j];
        total += fmaxf(acc, 0.f) * fc2[n];
    }
    red[threadIdx.x] = total;
    __syncthreads();
    for (int s = 128; s > 0; s >>= 1) {
        if (threadIdx.x < s) red[threadIdx.x] += red[threadIdx.x + s];
        __syncthreads();
    }
    if (threadIdx.x == 0) out[b] = red[0];
}

extern "C" void kernel_launch(void* const* d_in, const int* in_sizes, int n_in,
                              void* d_out, int out_size, void* d_ws, size_t ws_size,
                              hipStream_t stream) {
    (void)in_sizes; (void)n_in; (void)out_size;
    const float* x       = (const float*)d_in[0];
    const float* dec_i1  = (const float*)d_in[1];
    const float* W_emb   = (const float*)d_in[2];
    const float* enc_Wih = (const float*)d_in[3];
    const float* enc_Whh = (const float*)d_in[4];
    const float* enc_bih = (const float*)d_in[5];
    const float* enc_bhh = (const float*)d_in[6];
    const float* dec_Wih = (const float*)d_in[7];
    const float* dec_Whh = (const float*)d_in[8];
    const float* dec_bih = (const float*)d_in[9];
    const float* dec_bhh = (const float*)d_in[10];
    const float* W_q     = (const float*)d_in[11];
    const float* W_ref   = (const float*)d_in[12];
    const float* vv      = (const float*)d_in[13];
    const float* fc1     = (const float*)d_in[14];
    const float* fc2     = (const float*)d_in[15];
    float* out = (float*)d_out;

    const size_t BH = (size_t)BATCH * H;
    const size_t W4 = (size_t)4 * H * H;
    const size_t WS = (size_t)H * H;
    const size_t TBH = (size_t)TSTEPS * BATCH * H;

    unsigned* bar = (unsigned*)d_ws;       // 16 u32
    float* c_  = (float*)d_ws + 16;        // BH
    u16* hbuf  = (u16*)(c_ + BH);          // 4*BH u16: hi0, lo0, hi1, lo1
    float* Wc  = (float*)(hbuf + 4 * BH);  // 4H*2
    float* bc  = Wc + 4 * H * 2;           // 4H
    float* db  = bc + 4 * H;               // 4H
    u16* dhi   = (u16*)(db + 4 * H);       // BH
    u16* dlo   = dhi + BH;                 // BH
    u16* WeH   = dlo + BH;    u16* WeL  = WeH + W4;
    u16* WdiH  = WeL + W4;    u16* WdiL = WdiH + W4;
    u16* WdhH  = WdiL + W4;   u16* WdhL = WdhH + W4;
    u16* WqH   = WdhL + W4;   u16* WqL  = WqH + WS;
    u16* WrH   = WqL + WS;    u16* WrL  = WrH + WS;
    u16* ench  = WrL + WS;                 // TBH batch-major [b][t][h] bf16
    u16* u1r   = ench + TBH;               // TBH batch-major [b][t][h] bf16

    size_t needed = (size_t)((char*)(u1r + TBH) - (char*)d_ws);
    if (ws_size < needed) return;

    const int ENC_SMEM = 131072 + 16384;           // 147456
    const int DEC_SMEM = 131072 + 22528;           // 153600
    (void)hipFuncSetAttribute((const void*)persist_enc, hipFuncAttributeMaxDynamicSharedMemorySize, ENC_SMEM);
    (void)hipFuncSetAttribute((const void*)persist_dec, hipFuncAttributeMaxDynamicSharedMemorySize, DEC_SMEM);

    prep_kernel<<<8, 256, 0, stream>>>(W_emb, enc_Wih, enc_bih, enc_bhh, dec_bih, dec_bhh, Wc, bc, db);
    pack_w<<<(int)(W4 / 256), 256, 0, stream>>>(enc_Whh, WeH, WeL, (int)W4);
    pack_w<<<(int)(W4 / 256), 256, 0, stream>>>(dec_Wih, WdiH, WdiL, (int)W4);
    pack_w<<<(int)(W4 / 256), 256, 0, stream>>>(dec_Whh, WdhH, WdhL, (int)W4);
    pack_w<<<(int)(WS / 256), 256, 0, stream>>>(W_q, WqH, WqL, (int)WS);
    pack_w<<<(int)(WS / 256), 256, 0, stream>>>(W_ref, WrH, WrL, (int)WS);
    pack_w<<<(int)(BH / 256), 256, 0, stream>>>(dec_i1, dhi, dlo, (int)BH);
    // zero: bar(16) + c(BH) + hbuf(4BH u16 = 2BH f32), contiguous from d_ws
    zero4<<<(int)((16 + 3 * BH + 255) / 256), 256, 0, stream>>>((float*)d_ws, (int)(16 + 3 * BH));

    persist_enc<<<NBLK, NT, ENC_SMEM, stream>>>(x, Wc, bc, WeH, WeL, c_, hbuf, ench, bar);
    gemm_u1<<<TSTEPS * BATCH / 32, 256, 0, stream>>>(ench, WrH, WrL, u1r);
    persist_dec<<<NBLK, NT, DEC_SMEM, stream>>>(WdiH, WdiL, WdhH, WdhL, db, WqH, WqL,
                                                u1r, ench, vv, c_, hbuf, dhi, dlo, bar);
    final_kernel<<<BATCH, 256, 0, stream>>>(hbuf, hbuf + BH, fc1, fc2, out);
}

// Round 6
// 13190.533 us; speedup vs baseline: 1.3414x; 1.3414x over previous
//
#include <hip/hip_runtime.h>
#include <hip/hip_bf16.h>

#define H 512
#define TSTEPS 100
#define BATCH 512
#define KB 16          // 512 / 32 k-blocks
#define NBLK 256
#define NT 512
#define NGRP 8
#define GBLK 32        // blocks per group

typedef __attribute__((ext_vector_type(8))) short bf16x8;
typedef __attribute__((ext_vector_type(8))) unsigned short u16x8;
typedef __attribute__((ext_vector_type(4))) float f32x4;
typedef unsigned short u16;

__device__ __forceinline__ float bf2f(u16 u) {
    union { unsigned int i; float f; } z; z.i = ((unsigned int)u) << 16; return z.f;
}
__device__ __forceinline__ u16 f2bf(float f) {
    union { float f; unsigned int u; } z; z.f = f;
    unsigned int r = (z.u + 0x7fffu + ((z.u >> 16) & 1u)) >> 16;
    return (u16)r;
}
__device__ __forceinline__ float sigmoidf_(float x) { return 1.0f / (1.0f + __expf(-x)); }
__device__ __forceinline__ float ftanh(float x) {
    x = fminf(15.0f, fmaxf(-15.0f, x));
    float e = __expf(2.0f * x);
    return (e - 1.0f) / (e + 1.0f);
}
__device__ __forceinline__ f32x4 MF(bf16x8 a, bf16x8 b, f32x4 c) {
    return __builtin_amdgcn_mfma_f32_16x16x32_bf16(a, b, c, 0, 0, 0);
}

// packed fragment index for [M x 512] bf16, 16x32 frags; A and B share it so
// k-mapping errors cancel in the contraction.
__device__ __forceinline__ size_t pidx(int m, int k) {
    int kb = k >> 5, kin = k & 31;
    int lane = (m & 15) + (((kin >> 2) & 3) << 4);
    int j = (kin & 3) + ((kin >> 4) << 2);
    return ((size_t)((m >> 4) * KB + kb) * 64 + lane) * 8 + j;
}

// ---------------- group-local barrier (32 blocks; group-private cache lines) ----
__device__ __forceinline__ void gbar32(unsigned* bar, int grp) {
    __syncthreads();
    if (threadIdx.x == 0) {
        unsigned* cnt = &bar[grp * 32];
        unsigned* gen = &bar[grp * 32 + 16];
        unsigned g = __hip_atomic_load(gen, __ATOMIC_RELAXED, __HIP_MEMORY_SCOPE_AGENT);
        if (__hip_atomic_fetch_add(cnt, 1u, __ATOMIC_ACQ_REL, __HIP_MEMORY_SCOPE_AGENT) == GBLK - 1u) {
            __hip_atomic_store(cnt, 0u, __ATOMIC_RELAXED, __HIP_MEMORY_SCOPE_AGENT);
            __hip_atomic_fetch_add(gen, 1u, __ATOMIC_ACQ_REL, __HIP_MEMORY_SCOPE_AGENT);
        } else {
            while (__hip_atomic_load(gen, __ATOMIC_RELAXED, __HIP_MEMORY_SCOPE_AGENT) == g) {
                __builtin_amdgcn_s_sleep(2);
            }
            __threadfence();
        }
    }
    __syncthreads();
}

// ---------------- prep ----------------
__global__ void prep_kernel(const float* __restrict__ W_emb, const float* __restrict__ enc_Wih,
                            const float* __restrict__ enc_bih, const float* __restrict__ enc_bhh,
                            const float* __restrict__ dec_bih, const float* __restrict__ dec_bhh,
                            float* __restrict__ Wc, float* __restrict__ bc, float* __restrict__ db) {
    int g = blockIdx.x * blockDim.x + threadIdx.x;
    if (g >= 4 * H) return;
    float s0 = 0.f, s1 = 0.f;
    for (int j = 0; j < H; ++j) {
        float w = enc_Wih[(size_t)g * H + j];
        s0 += w * W_emb[j * 2 + 0];
        s1 += w * W_emb[j * 2 + 1];
    }
    Wc[g * 2 + 0] = s0; Wc[g * 2 + 1] = s1;
    bc[g] = enc_bih[g] + enc_bhh[g];
    db[g] = dec_bih[g] + dec_bhh[g];
}

__global__ void pack_w(const float* __restrict__ W, u16* __restrict__ hi, u16* __restrict__ lo,
                       int total) {
    int idx = blockIdx.x * 256 + threadIdx.x;
    if (idx >= total) return;
    int m = idx >> 9, k = idx & 511;
    float v = W[idx];
    u16 h16 = f2bf(v);
    u16 l16 = f2bf(v - bf2f(h16));
    size_t p = pidx(m, k);
    hi[p] = h16; lo[p] = l16;
}

__global__ void zero4(float* __restrict__ p, int n) {
    int i = blockIdx.x * blockDim.x + threadIdx.x;
    if (i < n) p[i] = 0.f;
}

// ---------------- persistent encoder: 8 independent groups of 32 blocks ----------------
// group grp=blk&7 owns batch rows [grp*64,(grp+1)*64); block n-slice nni=blk>>3.
__global__ __launch_bounds__(NT, 1) void persist_enc(
    const float* __restrict__ x, const float* __restrict__ Wc, const float* __restrict__ bc,
    const u16* __restrict__ WeH, const u16* __restrict__ WeL,
    float* __restrict__ cbuf, u16* __restrict__ hbuf,
    u16* __restrict__ ench, unsigned* __restrict__ bar) {
    extern __shared__ char smem[];
    u16* wlds = (u16*)smem;                    // [4 q][2 hl][16 kb][512] = 128 KB
    float* exch = (float*)(smem + 131072);     // [4 q][64 lb][16 col] = 16 KB
    const int tid = threadIdx.x;
    const int lane = tid & 63;
    const int w = tid >> 6;
    const int q = w & 3, jh = w >> 2;
    const int blk = blockIdx.x;
    const int grp = blk & 7, nni = blk >> 3;
    const size_t BHs = (size_t)BATCH * H;

    for (int c = 0; c < 8; ++c) {
        int cq = c >> 1, hl = c & 1;
        const u16x8* s8 = (const u16x8*)((hl ? WeL : WeH) + (size_t)((cq * 32 + nni) * KB) * 512);
        u16x8* d8 = (u16x8*)(wlds + c * 8192);
        for (int i = tid; i < 1024; i += NT) d8[i] = s8[i];
    }
    __syncthreads();

    for (int t = 0; t < TSTEPS; ++t) {
        const u16* Ah = hbuf + (size_t)(t & 1) * 2 * BHs;
        const u16* Al = Ah + BHs;
        u16* Hh = hbuf + (size_t)((t + 1) & 1) * 2 * BHs;
        u16* Hl = Hh + BHs;
        f32x4 acc[2] = {};
#pragma unroll 4
        for (int kb = 0; kb < KB; ++kb) {
            bf16x8 bh = *(const bf16x8*)&wlds[((q * 2 + 0) * KB + kb) * 512 + lane * 8];
            bf16x8 bl = *(const bf16x8*)&wlds[((q * 2 + 1) * KB + kb) * 512 + lane * 8];
#pragma unroll
            for (int jj = 0; jj < 2; ++jj) {
                int j = jh * 2 + jj;
                size_t ab = ((size_t)((grp * 4 + j) * KB + kb) * 64 + lane) * 8;
                bf16x8 ah = *(const bf16x8*)&Ah[ab];
                bf16x8 al = *(const bf16x8*)&Al[ab];
                acc[jj] = MF(ah, bh, acc[jj]);
                acc[jj] = MF(ah, bl, acc[jj]);
                acc[jj] = MF(al, bh, acc[jj]);
            }
        }
        const int col = lane & 15, rg = lane >> 4;
#pragma unroll
        for (int jj = 0; jj < 2; ++jj)
#pragma unroll
            for (int r = 0; r < 4; ++r)
                exch[(q * 64 + (jh * 2 + jj) * 16 + rg * 4 + r) * 16 + col] = acc[jj][r];
        __syncthreads();
#pragma unroll
        for (int k = 0; k < 2; ++k) {
            int cell = k * NT + tid;
            int lb = cell >> 4, cl = cell & 15;
            int b = grp * 64 + lb, n = nni * 16 + cl;
            float x0 = x[((size_t)b * TSTEPS + t) * 2 + 0];
            float x1 = x[((size_t)b * TSTEPS + t) * 2 + 1];
            float g[4];
#pragma unroll
            for (int qq = 0; qq < 4; ++qq)
                g[qq] = exch[(qq * 64 + lb) * 16 + cl] + bc[qq * H + n]
                      + x0 * Wc[(qq * H + n) * 2 + 0] + x1 * Wc[(qq * H + n) * 2 + 1];
            size_t ci = (size_t)b * H + n;
            float cn = sigmoidf_(g[1]) * cbuf[ci] + sigmoidf_(g[0]) * ftanh(g[2]);
            float hn = sigmoidf_(g[3]) * ftanh(cn);
            cbuf[ci] = cn;
            u16 hh = f2bf(hn), hl16 = f2bf(hn - bf2f(hh));
            size_t p = pidx(b, n);
            Hh[p] = hh; Hl[p] = hl16;
            ench[((size_t)b * TSTEPS + t) * H + n] = hh;   // batch-major
        }
        gbar32(bar, grp);
    }
}

// ---------------- persistent decoder: 8 independent groups of 32 blocks ----------------
__global__ __launch_bounds__(NT, 1) void persist_dec(
    const u16* __restrict__ WdiH, const u16* __restrict__ WdiL,
    const u16* __restrict__ WdhH, const u16* __restrict__ WdhL,
    const float* __restrict__ db,
    const u16* __restrict__ WqH, const u16* __restrict__ WqL,
    const u16* __restrict__ u1r, const u16* __restrict__ ench, const float* __restrict__ vv,
    float* __restrict__ cbuf, u16* __restrict__ hbuf,
    u16* __restrict__ dhi, u16* __restrict__ dlo,
    unsigned* __restrict__ bar) {
    extern __shared__ char smem[];
    u16* wlds = (u16*)smem;                    // [2 mat][4 q][16 kb][512] hi = 128 KB
    char* scratch = smem + 131072;             // 22.5 KB overlay region
    float* exch  = (float*)scratch;            // phase A: [4][64][16] = 16 KB
    float* u2row = (float*)scratch;            // phase C: [2][512] = 4 KB
    float* ssc   = (float*)(scratch + 4096);   // [2][100] scores
    float* ssm   = (float*)(scratch + 4928);   // [2][100] softmax
    f32x4* dacc  = (f32x4*)(scratch + 5760);   // [4 par][2 r][64 l][2] f32x4 = 16 KB
    const int tid = threadIdx.x;
    const int lane = tid & 63;
    const int w = tid >> 6;
    const int blk = blockIdx.x;
    const int grp = blk & 7, nni = blk >> 3;
    const size_t BHs = (size_t)BATCH * H;

    float vvr[8];
    {
        float4 v0 = *(const float4*)&vv[lane * 8];
        float4 v1 = *(const float4*)&vv[lane * 8 + 4];
        vvr[0] = v0.x; vvr[1] = v0.y; vvr[2] = v0.z; vvr[3] = v0.w;
        vvr[4] = v1.x; vvr[5] = v1.y; vvr[6] = v1.z; vvr[7] = v1.w;
    }

    for (int c = 0; c < 8; ++c) {
        int mat = c >> 2, cq = c & 3;
        const u16x8* s8 = (const u16x8*)((mat ? WdhH : WdiH) + (size_t)((cq * 32 + nni) * KB) * 512);
        u16x8* d8 = (u16x8*)(wlds + c * 8192);
        for (int i = tid; i < 1024; i += NT) d8[i] = s8[i];
    }
    __syncthreads();

    for (int s = 0; s < TSTEPS; ++s) {
        // ---- phase A: LSTM gates + cell update (rows grp*64..+64, cols nni*16..+16) ----
        {
            const u16* hAh = hbuf + (size_t)(s & 1) * 2 * BHs;
            const u16* hAl = hAh + BHs;
            u16* Hh = hbuf + (size_t)((s + 1) & 1) * 2 * BHs;
            u16* Hl = Hh + BHs;
            const int q = w & 3, jh = w >> 2;
            f32x4 acc[2] = {};
#pragma unroll
            for (int ph = 0; ph < 2; ++ph) {
                const u16* Ah = ph ? hAh : dhi;
                const u16* Al = ph ? hAl : dlo;
                const u16* Wl = ph ? WdhL : WdiL;
#pragma unroll 4
                for (int kb = 0; kb < KB; ++kb) {
                    bf16x8 bh = *(const bf16x8*)&wlds[((ph * 4 + q) * KB + kb) * 512 + lane * 8];
                    bf16x8 bl = *(const bf16x8*)&Wl[((size_t)((q * 32 + nni) * KB + kb) * 64 + lane) * 8];
#pragma unroll
                    for (int jj = 0; jj < 2; ++jj) {
                        int j = jh * 2 + jj;
                        size_t ab = ((size_t)((grp * 4 + j) * KB + kb) * 64 + lane) * 8;
                        bf16x8 ah = *(const bf16x8*)&Ah[ab];
                        bf16x8 al = *(const bf16x8*)&Al[ab];
                        acc[jj] = MF(ah, bh, acc[jj]);
                        acc[jj] = MF(ah, bl, acc[jj]);
                        acc[jj] = MF(al, bh, acc[jj]);
                    }
                }
            }
            const int col = lane & 15, rg = lane >> 4;
#pragma unroll
            for (int jj = 0; jj < 2; ++jj)
#pragma unroll
                for (int r = 0; r < 4; ++r)
                    exch[(q * 64 + (jh * 2 + jj) * 16 + rg * 4 + r) * 16 + col] = acc[jj][r];
            __syncthreads();
#pragma unroll
            for (int k = 0; k < 2; ++k) {
                int cell = k * NT + tid;
                int lb = cell >> 4, cl = cell & 15;
                int b = grp * 64 + lb, n = nni * 16 + cl;
                float g[4];
#pragma unroll
                for (int qq = 0; qq < 4; ++qq)
                    g[qq] = exch[(qq * 64 + lb) * 16 + cl] + db[qq * H + n];
                size_t ci = (size_t)b * H + n;
                float cn = sigmoidf_(g[1]) * cbuf[ci] + sigmoidf_(g[0]) * ftanh(g[2]);
                float hn = sigmoidf_(g[3]) * ftanh(cn);
                cbuf[ci] = cn;
                u16 hh = f2bf(hn), hl16 = f2bf(hn - bf2f(hh));
                size_t p = pidx(b, n);
                Hh[p] = hh; Hl[p] = hl16;
            }
        }
        if (s == TSTEPS - 1) break;
        gbar32(bar, grp);

        // ---- phase C: u2 for own 2 rows + attention ----
        {
            const u16* Ah = hbuf + (size_t)((s + 1) & 1) * 2 * BHs;
            const u16* Al = Ah + BHs;
            const int mf = grp * 4 + (nni >> 3);   // m-frag containing this block's 2 rows
            f32x4 acc[4] = {};
#pragma unroll 4
            for (int kb = 0; kb < KB; ++kb) {
                size_t ab = ((size_t)(mf * KB + kb) * 64 + lane) * 8;
                bf16x8 ah = *(const bf16x8*)&Ah[ab];
                bf16x8 al = *(const bf16x8*)&Al[ab];
#pragma unroll
                for (int f = 0; f < 4; ++f) {
                    int n16 = w * 4 + f;
                    size_t fb = ((size_t)(n16 * KB + kb) * 64 + lane) * 8;
                    bf16x8 bh = *(const bf16x8*)&WqH[fb];
                    bf16x8 bl = *(const bf16x8*)&WqL[fb];
                    acc[f] = MF(ah, bh, acc[f]);
                    acc[f] = MF(ah, bl, acc[f]);
                    acc[f] = MF(al, bh, acc[f]);
                }
            }
            const int col = lane & 15, rg = lane >> 4;
            const int t0 = (nni & 7) * 2;          // rows within the m-frag
#pragma unroll
            for (int f = 0; f < 4; ++f)
#pragma unroll
                for (int r = 0; r < 4; ++r) {
                    int m = rg * 4 + r;
                    int n = (w * 4 + f) * 16 + col;
                    if (m == t0)     u2row[n] = acc[f][r];
                    if (m == t0 + 1) u2row[512 + n] = acc[f][r];
                }
        }
        __syncthreads();
        {
            const int r = tid >> 8;          // 0..1
            const int par = (tid >> 6) & 3;  // contiguous 25-cc range per wave
            const int ccb = par * 25;
            const int b = grp * 64 + 2 * nni + r;
            float u2v[8];
            {
                float4 a0 = *(const float4*)&u2row[r * 512 + lane * 8];
                float4 a1 = *(const float4*)&u2row[r * 512 + lane * 8 + 4];
                u2v[0] = a0.x; u2v[1] = a0.y; u2v[2] = a0.z; u2v[3] = a0.w;
                u2v[4] = a1.x; u2v[5] = a1.y; u2v[6] = a1.z; u2v[7] = a1.w;
            }
            const u16* u1base = &u1r[(size_t)b * TSTEPS * H + lane * 8];
            const u16* ehbase = &ench[(size_t)b * TSTEPS * H + lane * 8];
            // scores: contiguous cc, 5-deep load batches
            for (int i0 = 0; i0 < 25; i0 += 5) {
                u16x8 uvv[5];
#pragma unroll
                for (int u = 0; u < 5; ++u)
                    uvv[u] = *(const u16x8*)&u1base[(size_t)(ccb + i0 + u) * H];
#pragma unroll
                for (int u = 0; u < 5; ++u) {
                    float pp = 0.f;
#pragma unroll
                    for (int j = 0; j < 8; ++j)
                        pp += vvr[j] * ftanh(bf2f(uvv[u][j]) + u2v[j]);
#pragma unroll
                    for (int off = 32; off; off >>= 1) pp += __shfl_xor(pp, off);
                    if (lane == 0) ssc[r * 100 + ccb + i0 + u] = pp;
                }
            }
            __syncthreads();
            if (tid < 128) {
                int r2 = tid >> 6, ln = tid & 63;
                float s1 = ssc[r2 * 100 + ln];
                float s2 = (ln + 64 < 100) ? ssc[r2 * 100 + ln + 64] : -1e30f;
                float m = fmaxf(s1, s2);
#pragma unroll
                for (int off = 32; off; off >>= 1) m = fmaxf(m, __shfl_xor(m, off));
                float e1 = __expf(s1 - m);
                float e2 = (ln + 64 < 100) ? __expf(s2 - m) : 0.f;
                float sum = e1 + e2;
#pragma unroll
                for (int off = 32; off; off >>= 1) sum += __shfl_xor(sum, off);
                float inv = 1.f / sum;
                ssm[r2 * 100 + ln] = e1 * inv;
                if (ln + 64 < 100) ssm[r2 * 100 + ln + 64] = e2 * inv;
            }
            __syncthreads();
            // glimpse
            float ga[8] = {};
            for (int i0 = 0; i0 < 25; i0 += 5) {
                u16x8 evv[5];
#pragma unroll
                for (int u = 0; u < 5; ++u)
                    evv[u] = *(const u16x8*)&ehbase[(size_t)(ccb + i0 + u) * H];
#pragma unroll
                for (int u = 0; u < 5; ++u) {
                    float a = ssm[r * 100 + ccb + i0 + u];
#pragma unroll
                    for (int j = 0; j < 8; ++j) ga[j] += a * bf2f(evv[u][j]);
                }
            }
            f32x4 g0 = {ga[0], ga[1], ga[2], ga[3]};
            f32x4 g1 = {ga[4], ga[5], ga[6], ga[7]};
            dacc[(((par * 2 + r) * 64) + lane) * 2 + 0] = g0;
            dacc[(((par * 2 + r) * 64) + lane) * 2 + 1] = g1;
            __syncthreads();
            if (tid < 128) {
                int r2 = tid >> 6, l = tid & 63;
                float fin[8];
#pragma unroll
                for (int j = 0; j < 8; ++j) fin[j] = 0.f;
#pragma unroll
                for (int pq = 0; pq < 4; ++pq) {
                    f32x4 d0 = dacc[(((pq * 2 + r2) * 64) + l) * 2 + 0];
                    f32x4 d1 = dacc[(((pq * 2 + r2) * 64) + l) * 2 + 1];
                    fin[0] += d0[0]; fin[1] += d0[1]; fin[2] += d0[2]; fin[3] += d0[3];
                    fin[4] += d1[0]; fin[5] += d1[1]; fin[6] += d1[2]; fin[7] += d1[3];
                }
                int b2 = grp * 64 + 2 * nni + r2;
                int h0 = l * 8;
#pragma unroll
                for (int qd = 0; qd < 2; ++qd) {
                    int k = h0 + 4 * qd;
                    size_t p = (((size_t)(b2 >> 4) * KB + (k >> 5)) * 64 + (b2 & 15)
                                + (((k >> 2) & 3) << 4)) * 8 + (((k >> 4) & 1) << 2);
                    float f0 = fin[4 * qd], f1 = fin[4 * qd + 1], f2 = fin[4 * qd + 2], f3 = fin[4 * qd + 3];
                    u16 a0 = f2bf(f0), a1 = f2bf(f1), a2 = f2bf(f2), a3 = f2bf(f3);
                    *(ushort4*)&dhi[p] = make_ushort4(a0, a1, a2, a3);
                    u16 c0 = f2bf(f0 - bf2f(a0)), c1 = f2bf(f1 - bf2f(a1));
                    u16 c2 = f2bf(f2 - bf2f(a2)), c3 = f2bf(f3 - bf2f(a3));
                    *(ushort4*)&dlo[p] = make_ushort4(c0, c1, c2, c3);
                }
            }
        }
        gbar32(bar, grp);
    }
}

// ---------------- u1 = ench @ W_ref.T (one-shot; rows are b*TSTEPS+cc) ----------------
__global__ __launch_bounds__(256) void gemm_u1(const u16* __restrict__ ench_row,
                                               const u16* __restrict__ Bh, const u16* __restrict__ Bl,
                                               u16* __restrict__ u1_row) {
    __shared__ u16 lds[2 * KB * 64 * 8];   // 32 KB
    const int tid = threadIdx.x;
    const int m0 = blockIdx.x * 32;
    {
        int r = tid >> 3;
        int o = tid & 7;
#pragma unroll
        for (int p8 = 0; p8 < 8; ++p8) {
            int k0 = (o + 8 * p8) * 8;
            const u16* src = &ench_row[(size_t)(m0 + r) * H + k0];
            ushort4 v0 = *(const ushort4*)&src[0];
            ushort4 v1 = *(const ushort4*)&src[4];
            int kb = k0 >> 5, kin0 = k0 & 31;
            int g0 = (kin0 >> 2) & 3;
            int jo = (kin0 >> 4) << 2;
            u16* base = &lds[(size_t)(((r >> 4) * KB + kb) * 64) * 8];
            *(ushort4*)&base[((r & 15) + 16 * g0) * 8 + jo] = v0;
            *(ushort4*)&base[((r & 15) + 16 * (g0 + 1)) * 8 + jo] = v1;
        }
    }
    __syncthreads();
    const int lane = tid & 63;
    const int w = tid >> 6;
    const int mw = w & 1, nh = w >> 1;
    for (int nc = 0; nc < 16; ++nc) {
        int n16 = nh * 16 + nc;
        f32x4 acc = {};
#pragma unroll 4
        for (int kb = 0; kb < KB; ++kb) {
            bf16x8 a = *(const bf16x8*)&lds[((mw * KB + kb) * 64 + lane) * 8];
            size_t fb = ((size_t)(n16 * KB + kb) * 64 + lane) * 8;
            bf16x8 bh = *(const bf16x8*)&Bh[fb];
            bf16x8 bl = *(const bf16x8*)&Bl[fb];
            acc = MF(a, bh, acc);
            acc = MF(a, bl, acc);
        }
        const int col = lane & 15, rg = lane >> 4;
#pragma unroll
        for (int r = 0; r < 4; ++r) {
            size_t mrow = (size_t)m0 + mw * 16 + rg * 4 + r;
            u1_row[mrow * H + n16 * 16 + col] = f2bf(acc[r]);
        }
    }
}

// ---------------- final ----------------
__global__ __launch_bounds__(256) void final_kernel(const u16* __restrict__ hi,
                                                    const u16* __restrict__ lo,
                                                    const float* __restrict__ fc1,
                                                    const float* __restrict__ fc2,
                                                    float* __restrict__ out) {
    const int b = blockIdx.x;
    __shared__ float hsh[H];
    __shared__ float red[256];
    for (int i = threadIdx.x; i < H; i += 256) {
        size_t p = pidx(b, i);
        hsh[i] = bf2f(hi[p]) + bf2f(lo[p]);
    }
    __syncthreads();
    float total = 0.f;
    for (int n = threadIdx.x; n < H; n += 256) {
        float acc = 0.f;
        for (int j = 0; j < H; ++j) acc += fc1[(size_t)n * H + j] * hsh[j];
        total += fmaxf(acc, 0.f) * fc2[n];
    }
    red[threadIdx.x] = total;
    __syncthreads();
    for (int s = 128; s > 0; s >>= 1) {
        if (threadIdx.x < s) red[threadIdx.x] += red[threadIdx.x + s];
        __syncthreads();
    }
    if (threadIdx.x == 0) out[b] = red[0];
}

extern "C" void kernel_launch(void* const* d_in, const int* in_sizes, int n_in,
                              void* d_out, int out_size, void* d_ws, size_t ws_size,
                              hipStream_t stream) {
    (void)in_sizes; (void)n_in; (void)out_size;
    const float* x       = (const float*)d_in[0];
    const float* dec_i1  = (const float*)d_in[1];
    const float* W_emb   = (const float*)d_in[2];
    const float* enc_Wih = (const float*)d_in[3];
    const float* enc_Whh = (const float*)d_in[4];
    const float* enc_bih = (const float*)d_in[5];
    const float* enc_bhh = (const float*)d_in[6];
    const float* dec_Wih = (const float*)d_in[7];
    const float* dec_Whh = (const float*)d_in[8];
    const float* dec_bih = (const float*)d_in[9];
    const float* dec_bhh = (const float*)d_in[10];
    const float* W_q     = (const float*)d_in[11];
    const float* W_ref   = (const float*)d_in[12];
    const float* vv      = (const float*)d_in[13];
    const float* fc1     = (const float*)d_in[14];
    const float* fc2     = (const float*)d_in[15];
    float* out = (float*)d_out;

    const size_t BH = (size_t)BATCH * H;
    const size_t W4 = (size_t)4 * H * H;
    const size_t WS = (size_t)H * H;
    const size_t TBH = (size_t)TSTEPS * BATCH * H;

    unsigned* bar = (unsigned*)d_ws;       // 8 groups x 32 u32 = 256 u32
    float* c_  = (float*)d_ws + 256;       // BH
    u16* hbuf  = (u16*)(c_ + BH);          // 4*BH u16: hi0, lo0, hi1, lo1
    float* Wc  = (float*)(hbuf + 4 * BH);  // 4H*2
    float* bc  = Wc + 4 * H * 2;           // 4H
    float* db  = bc + 4 * H;               // 4H
    u16* dhi   = (u16*)(db + 4 * H);       // BH
    u16* dlo   = dhi + BH;                 // BH
    u16* WeH   = dlo + BH;    u16* WeL  = WeH + W4;
    u16* WdiH  = WeL + W4;    u16* WdiL = WdiH + W4;
    u16* WdhH  = WdiL + W4;   u16* WdhL = WdhH + W4;
    u16* WqH   = WdhL + W4;   u16* WqL  = WqH + WS;
    u16* WrH   = WqL + WS;    u16* WrL  = WrH + WS;
    u16* ench  = WrL + WS;                 // TBH batch-major [b][t][h] bf16
    u16* u1r   = ench + TBH;               // TBH batch-major [b][t][h] bf16

    size_t needed = (size_t)((char*)(u1r + TBH) - (char*)d_ws);
    if (ws_size < needed) return;

    const int ENC_SMEM = 131072 + 16384;           // 147456
    const int DEC_SMEM = 131072 + 22528;           // 153600
    (void)hipFuncSetAttribute((const void*)persist_enc, hipFuncAttributeMaxDynamicSharedMemorySize, ENC_SMEM);
    (void)hipFuncSetAttribute((const void*)persist_dec, hipFuncAttributeMaxDynamicSharedMemorySize, DEC_SMEM);

    prep_kernel<<<8, 256, 0, stream>>>(W_emb, enc_Wih, enc_bih, enc_bhh, dec_bih, dec_bhh, Wc, bc, db);
    pack_w<<<(int)(W4 / 256), 256, 0, stream>>>(enc_Whh, WeH, WeL, (int)W4);
    pack_w<<<(int)(W4 / 256), 256, 0, stream>>>(dec_Wih, WdiH, WdiL, (int)W4);
    pack_w<<<(int)(W4 / 256), 256, 0, stream>>>(dec_Whh, WdhH, WdhL, (int)W4);
    pack_w<<<(int)(WS / 256), 256, 0, stream>>>(W_q, WqH, WqL, (int)WS);
    pack_w<<<(int)(WS / 256), 256, 0, stream>>>(W_ref, WrH, WrL, (int)WS);
    pack_w<<<(int)(BH / 256), 256, 0, stream>>>(dec_i1, dhi, dlo, (int)BH);
    // zero: bar(256 u32) + c(BH) + hbuf(4BH u16 = 2BH f32), contiguous from d_ws
    zero4<<<(int)((256 + 3 * BH + 255) / 256), 256, 0, stream>>>((float*)d_ws, (int)(256 + 3 * BH));

    persist_enc<<<NBLK, NT, ENC_SMEM, stream>>>(x, Wc, bc, WeH, WeL, c_, hbuf, ench, bar);
    gemm_u1<<<TSTEPS * BATCH / 32, 256, 0, stream>>>(ench, WrH, WrL, u1r);
    persist_dec<<<NBLK, NT, DEC_SMEM, stream>>>(WdiH, WdiL, WdhH, WdhL, db, WqH, WqL,
                                                u1r, ench, vv, c_, hbuf, dhi, dlo, bar);
    final_kernel<<<BATCH, 256, 0, stream>>>(hbuf, hbuf + BH, fc1, fc2, out);
}

// Round 7
// 12250.986 us; speedup vs baseline: 1.4442x; 1.0767x over previous
//
#include <hip/hip_runtime.h>
#include <hip/hip_bf16.h>

#define H 512
#define TSTEPS 100
#define BATCH 512
#define KB 16          // 512 / 32 k-blocks
#define NBLK 256
#define NT 1024
#define NGRP 8
#define GBLK 32        // blocks per group

typedef __attribute__((ext_vector_type(8))) short bf16x8;
typedef __attribute__((ext_vector_type(8))) unsigned short u16x8;
typedef __attribute__((ext_vector_type(4))) float f32x4;
typedef unsigned short u16;

__device__ __forceinline__ float bf2f(u16 u) {
    union { unsigned int i; float f; } z; z.i = ((unsigned int)u) << 16; return z.f;
}
__device__ __forceinline__ u16 f2bf(float f) {
    union { float f; unsigned int u; } z; z.f = f;
    unsigned int r = (z.u + 0x7fffu + ((z.u >> 16) & 1u)) >> 16;
    return (u16)r;
}
__device__ __forceinline__ float sigmoidf_(float x) { return 1.0f / (1.0f + __expf(-x)); }
__device__ __forceinline__ float ftanh(float x) {
    x = fminf(15.0f, fmaxf(-15.0f, x));
    float e = __expf(2.0f * x);
    return (e - 1.0f) / (e + 1.0f);
}
__device__ __forceinline__ f32x4 MF(bf16x8 a, bf16x8 b, f32x4 c) {
    return __builtin_amdgcn_mfma_f32_16x16x32_bf16(a, b, c, 0, 0, 0);
}

// packed fragment index for [M x 512] bf16, 16x32 frags; A and B share it so
// k-mapping errors cancel in the contraction.
__device__ __forceinline__ size_t pidx(int m, int k) {
    int kb = k >> 5, kin = k & 31;
    int lane = (m & 15) + (((kin >> 2) & 3) << 4);
    int j = (kin & 3) + ((kin >> 4) << 2);
    return ((size_t)((m >> 4) * KB + kb) * 64 + lane) * 8 + j;
}

// ---------------- group-local barrier (32 blocks; group-private cache lines) ----
__device__ __forceinline__ void gbar32(unsigned* bar, int grp) {
    __syncthreads();
    if (threadIdx.x == 0) {
        unsigned* cnt = &bar[grp * 32];
        unsigned* gen = &bar[grp * 32 + 16];
        unsigned g = __hip_atomic_load(gen, __ATOMIC_RELAXED, __HIP_MEMORY_SCOPE_AGENT);
        if (__hip_atomic_fetch_add(cnt, 1u, __ATOMIC_ACQ_REL, __HIP_MEMORY_SCOPE_AGENT) == GBLK - 1u) {
            __hip_atomic_store(cnt, 0u, __ATOMIC_RELAXED, __HIP_MEMORY_SCOPE_AGENT);
            __hip_atomic_fetch_add(gen, 1u, __ATOMIC_ACQ_REL, __HIP_MEMORY_SCOPE_AGENT);
        } else {
            while (__hip_atomic_load(gen, __ATOMIC_RELAXED, __HIP_MEMORY_SCOPE_AGENT) == g) {
                __builtin_amdgcn_s_sleep(2);
            }
            __threadfence();
        }
    }
    __syncthreads();
}

// ---------------- prep ----------------
__global__ void prep_kernel(const float* __restrict__ W_emb, const float* __restrict__ enc_Wih,
                            const float* __restrict__ enc_bih, const float* __restrict__ enc_bhh,
                            const float* __restrict__ dec_bih, const float* __restrict__ dec_bhh,
                            float* __restrict__ Wc, float* __restrict__ bc, float* __restrict__ db) {
    int g = blockIdx.x * blockDim.x + threadIdx.x;
    if (g >= 4 * H) return;
    float s0 = 0.f, s1 = 0.f;
    for (int j = 0; j < H; ++j) {
        float w = enc_Wih[(size_t)g * H + j];
        s0 += w * W_emb[j * 2 + 0];
        s1 += w * W_emb[j * 2 + 1];
    }
    Wc[g * 2 + 0] = s0; Wc[g * 2 + 1] = s1;
    bc[g] = enc_bih[g] + enc_bhh[g];
    db[g] = dec_bih[g] + dec_bhh[g];
}

__global__ void pack_w(const float* __restrict__ W, u16* __restrict__ hi, u16* __restrict__ lo,
                       int total) {
    int idx = blockIdx.x * 256 + threadIdx.x;
    if (idx >= total) return;
    int m = idx >> 9, k = idx & 511;
    float v = W[idx];
    u16 h16 = f2bf(v);
    u16 l16 = f2bf(v - bf2f(h16));
    size_t p = pidx(m, k);
    hi[p] = h16; lo[p] = l16;
}

__global__ void zero4(float* __restrict__ p, int n) {
    int i = blockIdx.x * blockDim.x + threadIdx.x;
    if (i < n) p[i] = 0.f;
}

// ---------------- persistent encoder: 16 waves, 8 groups of 32 blocks ----------------
// group grp=blk&7 owns batch rows [grp*64,(grp+1)*64); block n-slice nni=blk>>3.
// wave w: gate q=w&3, row-frag j=w>>2 (16 waves cover 4q x 4j).
__global__ __launch_bounds__(NT, 1) void persist_enc(
    const float* __restrict__ x, const float* __restrict__ Wc, const float* __restrict__ bc,
    const u16* __restrict__ WeH, const u16* __restrict__ WeL,
    float* __restrict__ cbuf, u16* __restrict__ hbuf,
    u16* __restrict__ ench, unsigned* __restrict__ bar) {
    extern __shared__ char smem[];
    u16* wlds = (u16*)smem;                    // [4 q][2 hl][16 kb][512] = 128 KB
    float* exch = (float*)(smem + 131072);     // [4 q][64 lb][16 col] = 16 KB
    const int tid = threadIdx.x;
    const int lane = tid & 63;
    const int w = tid >> 6;
    const int q = w & 3, j = w >> 2;
    const int blk = blockIdx.x;
    const int grp = blk & 7, nni = blk >> 3;
    const size_t BHs = (size_t)BATCH * H;

    for (int c = 0; c < 8; ++c) {
        int cq = c >> 1, hl = c & 1;
        const u16x8* s8 = (const u16x8*)((hl ? WeL : WeH) + (size_t)((cq * 32 + nni) * KB) * 512);
        u16x8* d8 = (u16x8*)(wlds + c * 8192);
        for (int i = tid; i < 1024; i += NT) d8[i] = s8[i];
    }
    __syncthreads();

    for (int t = 0; t < TSTEPS; ++t) {
        const u16* Ah = hbuf + (size_t)(t & 1) * 2 * BHs;
        const u16* Al = Ah + BHs;
        u16* Hh = hbuf + (size_t)((t + 1) & 1) * 2 * BHs;
        u16* Hl = Hh + BHs;
        f32x4 acc = {};
#pragma unroll 4
        for (int kb = 0; kb < KB; ++kb) {
            bf16x8 bh = *(const bf16x8*)&wlds[((q * 2 + 0) * KB + kb) * 512 + lane * 8];
            bf16x8 bl = *(const bf16x8*)&wlds[((q * 2 + 1) * KB + kb) * 512 + lane * 8];
            size_t ab = ((size_t)((grp * 4 + j) * KB + kb) * 64 + lane) * 8;
            bf16x8 ah = *(const bf16x8*)&Ah[ab];
            bf16x8 al = *(const bf16x8*)&Al[ab];
            acc = MF(ah, bh, acc);
            acc = MF(ah, bl, acc);
            acc = MF(al, bh, acc);
        }
        const int col = lane & 15, rg = lane >> 4;
#pragma unroll
        for (int r = 0; r < 4; ++r)
            exch[(q * 64 + j * 16 + rg * 4 + r) * 16 + col] = acc[r];
        __syncthreads();
        {
            int lb = tid >> 4, cl = tid & 15;
            int b = grp * 64 + lb, n = nni * 16 + cl;
            float x0 = x[((size_t)b * TSTEPS + t) * 2 + 0];
            float x1 = x[((size_t)b * TSTEPS + t) * 2 + 1];
            float g[4];
#pragma unroll
            for (int qq = 0; qq < 4; ++qq)
                g[qq] = exch[(qq * 64 + lb) * 16 + cl] + bc[qq * H + n]
                      + x0 * Wc[(qq * H + n) * 2 + 0] + x1 * Wc[(qq * H + n) * 2 + 1];
            size_t ci = (size_t)b * H + n;
            float cn = sigmoidf_(g[1]) * cbuf[ci] + sigmoidf_(g[0]) * ftanh(g[2]);
            float hn = sigmoidf_(g[3]) * ftanh(cn);
            cbuf[ci] = cn;
            u16 hh = f2bf(hn), hl16 = f2bf(hn - bf2f(hh));
            size_t p = pidx(b, n);
            Hh[p] = hh; Hl[p] = hl16;
            ench[((size_t)b * TSTEPS + t) * H + n] = hh;   // batch-major
        }
        gbar32(bar, grp);
    }
}

// ---------------- persistent decoder: 16 waves, 8 groups of 32 blocks ----------------
__global__ __launch_bounds__(NT, 1) void persist_dec(
    const u16* __restrict__ WdiH, const u16* __restrict__ WdiL,
    const u16* __restrict__ WdhH, const u16* __restrict__ WdhL,
    const float* __restrict__ db,
    const u16* __restrict__ WqH, const u16* __restrict__ WqL,
    const u16* __restrict__ u1r, const u16* __restrict__ ench, const float* __restrict__ vv,
    float* __restrict__ cbuf, u16* __restrict__ hbuf,
    u16* __restrict__ dhi, u16* __restrict__ dlo,
    unsigned* __restrict__ bar) {
    extern __shared__ char smem[];
    u16* wlds = (u16*)smem;                    // [2 mat][4 q][16 kb][512] hi = 128 KB
    char* scratch = smem + 131072;             // 22 KB overlay region
    float* exch  = (float*)scratch;            // phase A: [4][64][16] = 16 KB
    float* u2row = (float*)scratch;            // phase C: [2][512] = 4 KB
    float* ssc   = (float*)(scratch + 4096);   // [2][100] scores
    float* ssm   = (float*)(scratch + 4928);   // [2][100] softmax
    f32x4* dacc  = (f32x4*)(scratch + 5760);   // [4 slot][2 r][64 l][2] f32x4 = 16 KB
    const int tid = threadIdx.x;
    const int lane = tid & 63;
    const int w = tid >> 6;
    const int blk = blockIdx.x;
    const int grp = blk & 7, nni = blk >> 3;
    const size_t BHs = (size_t)BATCH * H;

    float vvr[8];
    {
        float4 v0 = *(const float4*)&vv[lane * 8];
        float4 v1 = *(const float4*)&vv[lane * 8 + 4];
        vvr[0] = v0.x; vvr[1] = v0.y; vvr[2] = v0.z; vvr[3] = v0.w;
        vvr[4] = v1.x; vvr[5] = v1.y; vvr[6] = v1.z; vvr[7] = v1.w;
    }

    for (int c = 0; c < 8; ++c) {
        int mat = c >> 2, cq = c & 3;
        const u16x8* s8 = (const u16x8*)((mat ? WdhH : WdiH) + (size_t)((cq * 32 + nni) * KB) * 512);
        u16x8* d8 = (u16x8*)(wlds + c * 8192);
        for (int i = tid; i < 1024; i += NT) d8[i] = s8[i];
    }
    __syncthreads();

    for (int s = 0; s < TSTEPS; ++s) {
        // ---- phase A: LSTM gates + cell update; wave = (q, j) ----
        {
            const u16* hAh = hbuf + (size_t)(s & 1) * 2 * BHs;
            const u16* hAl = hAh + BHs;
            u16* Hh = hbuf + (size_t)((s + 1) & 1) * 2 * BHs;
            u16* Hl = Hh + BHs;
            const int q = w & 3, j = w >> 2;
            f32x4 acc = {};
#pragma unroll
            for (int ph = 0; ph < 2; ++ph) {
                const u16* Ah = ph ? hAh : dhi;
                const u16* Al = ph ? hAl : dlo;
                const u16* Wl = ph ? WdhL : WdiL;
#pragma unroll 4
                for (int kb = 0; kb < KB; ++kb) {
                    bf16x8 bh = *(const bf16x8*)&wlds[((ph * 4 + q) * KB + kb) * 512 + lane * 8];
                    bf16x8 bl = *(const bf16x8*)&Wl[((size_t)((q * 32 + nni) * KB + kb) * 64 + lane) * 8];
                    size_t ab = ((size_t)((grp * 4 + j) * KB + kb) * 64 + lane) * 8;
                    bf16x8 ah = *(const bf16x8*)&Ah[ab];
                    bf16x8 al = *(const bf16x8*)&Al[ab];
                    acc = MF(ah, bh, acc);
                    acc = MF(ah, bl, acc);
                    acc = MF(al, bh, acc);
                }
            }
            const int col = lane & 15, rg = lane >> 4;
#pragma unroll
            for (int r = 0; r < 4; ++r)
                exch[(q * 64 + j * 16 + rg * 4 + r) * 16 + col] = acc[r];
            __syncthreads();
            {
                int lb = tid >> 4, cl = tid & 15;
                int b = grp * 64 + lb, n = nni * 16 + cl;
                float g[4];
#pragma unroll
                for (int qq = 0; qq < 4; ++qq)
                    g[qq] = exch[(qq * 64 + lb) * 16 + cl] + db[qq * H + n];
                size_t ci = (size_t)b * H + n;
                float cn = sigmoidf_(g[1]) * cbuf[ci] + sigmoidf_(g[0]) * ftanh(g[2]);
                float hn = sigmoidf_(g[3]) * ftanh(cn);
                cbuf[ci] = cn;
                u16 hh = f2bf(hn), hl16 = f2bf(hn - bf2f(hh));
                size_t p = pidx(b, n);
                Hh[p] = hh; Hl[p] = hl16;
            }
        }
        if (s == TSTEPS - 1) break;
        gbar32(bar, grp);

        // ---- phase C: u2 for own 2 rows + attention ----
        {
            const u16* Ah = hbuf + (size_t)((s + 1) & 1) * 2 * BHs;
            const u16* Al = Ah + BHs;
            const int mf = grp * 4 + (nni >> 3);   // m-frag containing this block's 2 rows
            f32x4 acc[2] = {};
#pragma unroll 4
            for (int kb = 0; kb < KB; ++kb) {
                size_t ab = ((size_t)(mf * KB + kb) * 64 + lane) * 8;
                bf16x8 ah = *(const bf16x8*)&Ah[ab];
                bf16x8 al = *(const bf16x8*)&Al[ab];
#pragma unroll
                for (int f = 0; f < 2; ++f) {
                    int n16 = w * 2 + f;
                    size_t fb = ((size_t)(n16 * KB + kb) * 64 + lane) * 8;
                    bf16x8 bh = *(const bf16x8*)&WqH[fb];
                    bf16x8 bl = *(const bf16x8*)&WqL[fb];
                    acc[f] = MF(ah, bh, acc[f]);
                    acc[f] = MF(ah, bl, acc[f]);
                    acc[f] = MF(al, bh, acc[f]);
                }
            }
            const int col = lane & 15, rg = lane >> 4;
            const int t0 = (nni & 7) * 2;          // rows within the m-frag
#pragma unroll
            for (int f = 0; f < 2; ++f)
#pragma unroll
                for (int r = 0; r < 4; ++r) {
                    int m = rg * 4 + r;
                    int n = (w * 2 + f) * 16 + col;
                    if (m == t0)     u2row[n] = acc[f][r];
                    if (m == t0 + 1) u2row[512 + n] = acc[f][r];
                }
        }
        __syncthreads();
        {
            const int r = tid >> 9;          // 0..1
            const int par = (tid >> 6) & 7;  // 8 cc-partitions per row
            const int cnt = (par < 4) ? 13 : 12;   // cc = par + 8*i, i < cnt
            const int b = grp * 64 + 2 * nni + r;
            float u2v[8];
            {
                float4 a0 = *(const float4*)&u2row[r * 512 + lane * 8];
                float4 a1 = *(const float4*)&u2row[r * 512 + lane * 8 + 4];
                u2v[0] = a0.x; u2v[1] = a0.y; u2v[2] = a0.z; u2v[3] = a0.w;
                u2v[4] = a1.x; u2v[5] = a1.y; u2v[6] = a1.z; u2v[7] = a1.w;
            }
            const u16* u1base = &u1r[(size_t)b * TSTEPS * H + lane * 8];
            const u16* ehbase = &ench[(size_t)b * TSTEPS * H + lane * 8];
            // scores: 5-deep load batches, wave-uniform predication
            for (int i0 = 0; i0 < 13; i0 += 5) {
                u16x8 uvv[5];
#pragma unroll
                for (int u = 0; u < 5; ++u) {
                    int i = i0 + u;
                    if (i < cnt)
                        uvv[u] = *(const u16x8*)&u1base[(size_t)(par + 8 * i) * H];
                }
#pragma unroll
                for (int u = 0; u < 5; ++u) {
                    int i = i0 + u;
                    if (i < cnt) {
                        float pp = 0.f;
#pragma unroll
                        for (int jj = 0; jj < 8; ++jj)
                            pp += vvr[jj] * ftanh(bf2f(uvv[u][jj]) + u2v[jj]);
#pragma unroll
                        for (int off = 32; off; off >>= 1) pp += __shfl_xor(pp, off);
                        if (lane == 0) ssc[r * 100 + par + 8 * i] = pp;
                    }
                }
            }
            __syncthreads();
            if (tid < 128) {
                int r2 = tid >> 6, ln = tid & 63;
                float s1 = ssc[r2 * 100 + ln];
                float s2 = (ln + 64 < 100) ? ssc[r2 * 100 + ln + 64] : -1e30f;
                float m = fmaxf(s1, s2);
#pragma unroll
                for (int off = 32; off; off >>= 1) m = fmaxf(m, __shfl_xor(m, off));
                float e1 = __expf(s1 - m);
                float e2 = (ln + 64 < 100) ? __expf(s2 - m) : 0.f;
                float sum = e1 + e2;
#pragma unroll
                for (int off = 32; off; off >>= 1) sum += __shfl_xor(sum, off);
                float inv = 1.f / sum;
                ssm[r2 * 100 + ln] = e1 * inv;
                if (ln + 64 < 100) ssm[r2 * 100 + ln + 64] = e2 * inv;
            }
            __syncthreads();
            // glimpse (same cc mapping)
            float ga[8] = {};
            for (int i0 = 0; i0 < 13; i0 += 5) {
                u16x8 evv[5];
#pragma unroll
                for (int u = 0; u < 5; ++u) {
                    int i = i0 + u;
                    if (i < cnt)
                        evv[u] = *(const u16x8*)&ehbase[(size_t)(par + 8 * i) * H];
                }
#pragma unroll
                for (int u = 0; u < 5; ++u) {
                    int i = i0 + u;
                    if (i < cnt) {
                        float a = ssm[r * 100 + par + 8 * i];
#pragma unroll
                        for (int jj = 0; jj < 8; ++jj) ga[jj] += a * bf2f(evv[u][jj]);
                    }
                }
            }
            f32x4 g0 = {ga[0], ga[1], ga[2], ga[3]};
            f32x4 g1 = {ga[4], ga[5], ga[6], ga[7]};
            // deterministic two-round accumulate: slot s holds par=s + par=s+4
            if (par < 4) {
                dacc[(((par * 2 + r) * 64) + lane) * 2 + 0] = g0;
                dacc[(((par * 2 + r) * 64) + lane) * 2 + 1] = g1;
            }
            __syncthreads();
            if (par >= 4) {
                int slot = par - 4;
                f32x4 t0 = dacc[(((slot * 2 + r) * 64) + lane) * 2 + 0];
                f32x4 t1 = dacc[(((slot * 2 + r) * 64) + lane) * 2 + 1];
                dacc[(((slot * 2 + r) * 64) + lane) * 2 + 0] = t0 + g0;
                dacc[(((slot * 2 + r) * 64) + lane) * 2 + 1] = t1 + g1;
            }
            __syncthreads();
            if (tid < 128) {
                int r2 = tid >> 6, l = tid & 63;
                float fin[8];
#pragma unroll
                for (int jj = 0; jj < 8; ++jj) fin[jj] = 0.f;
#pragma unroll
                for (int sl = 0; sl < 4; ++sl) {
                    f32x4 d0 = dacc[(((sl * 2 + r2) * 64) + l) * 2 + 0];
                    f32x4 d1 = dacc[(((sl * 2 + r2) * 64) + l) * 2 + 1];
                    fin[0] += d0[0]; fin[1] += d0[1]; fin[2] += d0[2]; fin[3] += d0[3];
                    fin[4] += d1[0]; fin[5] += d1[1]; fin[6] += d1[2]; fin[7] += d1[3];
                }
                int b2 = grp * 64 + 2 * nni + r2;
                int h0 = l * 8;
#pragma unroll
                for (int qd = 0; qd < 2; ++qd) {
                    int k = h0 + 4 * qd;
                    size_t p = (((size_t)(b2 >> 4) * KB + (k >> 5)) * 64 + (b2 & 15)
                                + (((k >> 2) & 3) << 4)) * 8 + (((k >> 4) & 1) << 2);
                    float f0 = fin[4 * qd], f1 = fin[4 * qd + 1], f2 = fin[4 * qd + 2], f3 = fin[4 * qd + 3];
                    u16 a0 = f2bf(f0), a1 = f2bf(f1), a2 = f2bf(f2), a3 = f2bf(f3);
                    *(ushort4*)&dhi[p] = make_ushort4(a0, a1, a2, a3);
                    u16 c0 = f2bf(f0 - bf2f(a0)), c1 = f2bf(f1 - bf2f(a1));
                    u16 c2 = f2bf(f2 - bf2f(a2)), c3 = f2bf(f3 - bf2f(a3));
                    *(ushort4*)&dlo[p] = make_ushort4(c0, c1, c2, c3);
                }
            }
        }
        gbar32(bar, grp);
    }
}

// ---------------- u1 = ench @ W_ref.T (one-shot; rows are b*TSTEPS+cc) ----------------
__global__ __launch_bounds__(256) void gemm_u1(const u16* __restrict__ ench_row,
                                               const u16* __restrict__ Bh, const u16* __restrict__ Bl,
                                               u16* __restrict__ u1_row) {
    __shared__ u16 lds[2 * KB * 64 * 8];   // 32 KB
    const int tid = threadIdx.x;
    const int m0 = blockIdx.x * 32;
    {
        int r = tid >> 3;
        int o = tid & 7;
#pragma unroll
        for (int p8 = 0; p8 < 8; ++p8) {
            int k0 = (o + 8 * p8) * 8;
            const u16* src = &ench_row[(size_t)(m0 + r) * H + k0];
            ushort4 v0 = *(const ushort4*)&src[0];
            ushort4 v1 = *(const ushort4*)&src[4];
            int kb = k0 >> 5, kin0 = k0 & 31;
            int g0 = (kin0 >> 2) & 3;
            int jo = (kin0 >> 4) << 2;
            u16* base = &lds[(size_t)(((r >> 4) * KB + kb) * 64) * 8];
            *(ushort4*)&base[((r & 15) + 16 * g0) * 8 + jo] = v0;
            *(ushort4*)&base[((r & 15) + 16 * (g0 + 1)) * 8 + jo] = v1;
        }
    }
    __syncthreads();
    const int lane = tid & 63;
    const int w = tid >> 6;
    const int mw = w & 1, nh = w >> 1;
    for (int nc = 0; nc < 16; ++nc) {
        int n16 = nh * 16 + nc;
        f32x4 acc = {};
#pragma unroll 4
        for (int kb = 0; kb < KB; ++kb) {
            bf16x8 a = *(const bf16x8*)&lds[((mw * KB + kb) * 64 + lane) * 8];
            size_t fb = ((size_t)(n16 * KB + kb) * 64 + lane) * 8;
            bf16x8 bh = *(const bf16x8*)&Bh[fb];
            bf16x8 bl = *(const bf16x8*)&Bl[fb];
            acc = MF(a, bh, acc);
            acc = MF(a, bl, acc);
        }
        const int col = lane & 15, rg = lane >> 4;
#pragma unroll
        for (int r = 0; r < 4; ++r) {
            size_t mrow = (size_t)m0 + mw * 16 + rg * 4 + r;
            u1_row[mrow * H + n16 * 16 + col] = f2bf(acc[r]);
        }
    }
}

// ---------------- final ----------------
__global__ __launch_bounds__(256) void final_kernel(const u16* __restrict__ hi,
                                                    const u16* __restrict__ lo,
                                                    const float* __restrict__ fc1,
                                                    const float* __restrict__ fc2,
                                                    float* __restrict__ out) {
    const int b = blockIdx.x;
    __shared__ float hsh[H];
    __shared__ float red[256];
    for (int i = threadIdx.x; i < H; i += 256) {
        size_t p = pidx(b, i);
        hsh[i] = bf2f(hi[p]) + bf2f(lo[p]);
    }
    __syncthreads();
    float total = 0.f;
    for (int n = threadIdx.x; n < H; n += 256) {
        float acc = 0.f;
        for (int j = 0; j < H; ++j) acc += fc1[(size_t)n * H + j] * hsh[j];
        total += fmaxf(acc, 0.f) * fc2[n];
    }
    red[threadIdx.x] = total;
    __syncthreads();
    for (int s = 128; s > 0; s >>= 1) {
        if (threadIdx.x < s) red[threadIdx.x] += red[threadIdx.x + s];
        __syncthreads();
    }
    if (threadIdx.x == 0) out[b] = red[0];
}

extern "C" void kernel_launch(void* const* d_in, const int* in_sizes, int n_in,
                              void* d_out, int out_size, void* d_ws, size_t ws_size,
                              hipStream_t stream) {
    (void)in_sizes; (void)n_in; (void)out_size;
    const float* x       = (const float*)d_in[0];
    const float* dec_i1  = (const float*)d_in[1];
    const float* W_emb   = (const float*)d_in[2];
    const float* enc_Wih = (const float*)d_in[3];
    const float* enc_Whh = (const float*)d_in[4];
    const float* enc_bih = (const float*)d_in[5];
    const float* enc_bhh = (const float*)d_in[6];
    const float* dec_Wih = (const float*)d_in[7];
    const float* dec_Whh = (const float*)d_in[8];
    const float* dec_bih = (const float*)d_in[9];
    const float* dec_bhh = (const float*)d_in[10];
    const float* W_q     = (const float*)d_in[11];
    const float* W_ref   = (const float*)d_in[12];
    const float* vv      = (const float*)d_in[13];
    const float* fc1     = (const float*)d_in[14];
    const float* fc2     = (const float*)d_in[15];
    float* out = (float*)d_out;

    const size_t BH = (size_t)BATCH * H;
    const size_t W4 = (size_t)4 * H * H;
    const size_t WS = (size_t)H * H;
    const size_t TBH = (size_t)TSTEPS * BATCH * H;

    unsigned* bar = (unsigned*)d_ws;       // 8 groups x 32 u32 = 256 u32
    float* c_  = (float*)d_ws + 256;       // BH
    u16* hbuf  = (u16*)(c_ + BH);          // 4*BH u16: hi0, lo0, hi1, lo1
    float* Wc  = (float*)(hbuf + 4 * BH);  // 4H*2
    float* bc  = Wc + 4 * H * 2;           // 4H
    float* db  = bc + 4 * H;               // 4H
    u16* dhi   = (u16*)(db + 4 * H);       // BH
    u16* dlo   = dhi + BH;                 // BH
    u16* WeH   = dlo + BH;    u16* WeL  = WeH + W4;
    u16* WdiH  = WeL + W4;    u16* WdiL = WdiH + W4;
    u16* WdhH  = WdiL + W4;   u16* WdhL = WdhH + W4;
    u16* WqH   = WdhL + W4;   u16* WqL  = WqH + WS;
    u16* WrH   = WqL + WS;    u16* WrL  = WrH + WS;
    u16* ench  = WrL + WS;                 // TBH batch-major [b][t][h] bf16
    u16* u1r   = ench + TBH;               // TBH batch-major [b][t][h] bf16

    size_t needed = (size_t)((char*)(u1r + TBH) - (char*)d_ws);
    if (ws_size < needed) return;

    const int ENC_SMEM = 131072 + 16384;           // 147456
    const int DEC_SMEM = 131072 + 22528;           // 153600
    (void)hipFuncSetAttribute((const void*)persist_enc, hipFuncAttributeMaxDynamicSharedMemorySize, ENC_SMEM);
    (void)hipFuncSetAttribute((const void*)persist_dec, hipFuncAttributeMaxDynamicSharedMemorySize, DEC_SMEM);

    prep_kernel<<<8, 256, 0, stream>>>(W_emb, enc_Wih, enc_bih, enc_bhh, dec_bih, dec_bhh, Wc, bc, db);
    pack_w<<<(int)(W4 / 256), 256, 0, stream>>>(enc_Whh, WeH, WeL, (int)W4);
    pack_w<<<(int)(W4 / 256), 256, 0, stream>>>(dec_Wih, WdiH, WdiL, (int)W4);
    pack_w<<<(int)(W4 / 256), 256, 0, stream>>>(dec_Whh, WdhH, WdhL, (int)W4);
    pack_w<<<(int)(WS / 256), 256, 0, stream>>>(W_q, WqH, WqL, (int)WS);
    pack_w<<<(int)(WS / 256), 256, 0, stream>>>(W_ref, WrH, WrL, (int)WS);
    pack_w<<<(int)(BH / 256), 256, 0, stream>>>(dec_i1, dhi, dlo, (int)BH);
    // zero: bar(256 u32) + c(BH) + hbuf(4BH u16 = 2BH f32), contiguous from d_ws
    zero4<<<(int)((256 + 3 * BH + 255) / 256), 256, 0, stream>>>((float*)d_ws, (int)(256 + 3 * BH));

    persist_enc<<<NBLK, NT, ENC_SMEM, stream>>>(x, Wc, bc, WeH, WeL, c_, hbuf, ench, bar);
    gemm_u1<<<TSTEPS * BATCH / 32, 256, 0, stream>>>(ench, WrH, WrL, u1r);
    persist_dec<<<NBLK, NT, DEC_SMEM, stream>>>(WdiH, WdiL, WdhH, WdhL, db, WqH, WqL,
                                                u1r, ench, vv, c_, hbuf, dhi, dlo, bar);
    final_kernel<<<BATCH, 256, 0, stream>>>(hbuf, hbuf + BH, fc1, fc2, out);
}

// Round 8
// 11175.038 us; speedup vs baseline: 1.5833x; 1.0963x over previous
//
#include <hip/hip_runtime.h>
#include <hip/hip_bf16.h>

#define H 512
#define TSTEPS 100
#define BATCH 512
#define KB 16          // 512 / 32 k-blocks
#define NBLK 256
#define NT 1024
#define NGRP 8
#define GBLK 32        // blocks per group

typedef __attribute__((ext_vector_type(8))) short bf16x8;
typedef __attribute__((ext_vector_type(8))) unsigned short u16x8;
typedef __attribute__((ext_vector_type(4))) float f32x4;
typedef unsigned short u16;

__device__ __forceinline__ float bf2f(u16 u) {
    union { unsigned int i; float f; } z; z.i = ((unsigned int)u) << 16; return z.f;
}
__device__ __forceinline__ u16 f2bf(float f) {
    union { float f; unsigned int u; } z; z.f = f;
    unsigned int r = (z.u + 0x7fffu + ((z.u >> 16) & 1u)) >> 16;
    return (u16)r;
}
__device__ __forceinline__ float sigmoidf_(float x) { return 1.0f / (1.0f + __expf(-x)); }
__device__ __forceinline__ float ftanh(float x) {
    x = fminf(15.0f, fmaxf(-15.0f, x));
    float e = __expf(2.0f * x);
    return (e - 1.0f) / (e + 1.0f);
}
__device__ __forceinline__ f32x4 MF(bf16x8 a, bf16x8 b, f32x4 c) {
    return __builtin_amdgcn_mfma_f32_16x16x32_bf16(a, b, c, 0, 0, 0);
}

// packed fragment index for [M x 512] bf16, 16x32 frags; A and B share it so
// k-mapping errors cancel in the contraction.
__device__ __forceinline__ size_t pidx(int m, int k) {
    int kb = k >> 5, kin = k & 31;
    int lane = (m & 15) + (((kin >> 2) & 3) << 4);
    int j = (kin & 3) + ((kin >> 4) << 2);
    return ((size_t)((m >> 4) * KB + kb) * 64 + lane) * 8 + j;
}

// ---------------- flag barrier: 1 release-store per block, parallel poll ----------------
// flags[(grp*32+bib)*16]: 64B-strided, monotonically increasing step values.
__device__ __forceinline__ void fbar(unsigned* flags, int grp, int bib, unsigned target) {
    __syncthreads();
    if (threadIdx.x < 64) {
        if (threadIdx.x == 0)
            __hip_atomic_store(&flags[(grp * 32 + bib) * 16], target,
                               __ATOMIC_RELEASE, __HIP_MEMORY_SCOPE_AGENT);
        const int l = threadIdx.x;
        bool done;
        do {
            unsigned v = target;
            if (l < 32)
                v = __hip_atomic_load(&flags[(grp * 32 + l) * 16],
                                      __ATOMIC_RELAXED, __HIP_MEMORY_SCOPE_AGENT);
            done = __all((int)(v >= target));
            if (!done) __builtin_amdgcn_s_sleep(1);
        } while (!done);
        __threadfence();   // acquire for peer data published before their release-store
    }
    __syncthreads();
}

// ---------------- prep ----------------
__global__ void prep_kernel(const float* __restrict__ W_emb, const float* __restrict__ enc_Wih,
                            const float* __restrict__ enc_bih, const float* __restrict__ enc_bhh,
                            const float* __restrict__ dec_bih, const float* __restrict__ dec_bhh,
                            float* __restrict__ Wc, float* __restrict__ bc, float* __restrict__ db) {
    int g = blockIdx.x * blockDim.x + threadIdx.x;
    if (g >= 4 * H) return;
    float s0 = 0.f, s1 = 0.f;
    for (int j = 0; j < H; ++j) {
        float w = enc_Wih[(size_t)g * H + j];
        s0 += w * W_emb[j * 2 + 0];
        s1 += w * W_emb[j * 2 + 1];
    }
    Wc[g * 2 + 0] = s0; Wc[g * 2 + 1] = s1;
    bc[g] = enc_bih[g] + enc_bhh[g];
    db[g] = dec_bih[g] + dec_bhh[g];
}

__global__ void pack_w(const float* __restrict__ W, u16* __restrict__ hi, u16* __restrict__ lo,
                       int total) {
    int idx = blockIdx.x * 256 + threadIdx.x;
    if (idx >= total) return;
    int m = idx >> 9, k = idx & 511;
    float v = W[idx];
    u16 h16 = f2bf(v);
    u16 l16 = f2bf(v - bf2f(h16));
    size_t p = pidx(m, k);
    hi[p] = h16; lo[p] = l16;
}

__global__ void zero4(float* __restrict__ p, int n) {
    int i = blockIdx.x * blockDim.x + threadIdx.x;
    if (i < n) p[i] = 0.f;
}

// ---------------- persistent encoder: 16 waves, 8 groups of 32 blocks ----------------
__global__ __launch_bounds__(NT, 1) void persist_enc(
    const float* __restrict__ x, const float* __restrict__ Wc, const float* __restrict__ bc,
    const u16* __restrict__ WeH, const u16* __restrict__ WeL,
    float* __restrict__ cbuf, u16* __restrict__ hbuf,
    u16* __restrict__ ench, unsigned* __restrict__ fE) {
    extern __shared__ char smem[];
    u16* wlds = (u16*)smem;                    // [4 q][2 hl][16 kb][512] = 128 KB
    float* exch = (float*)(smem + 131072);     // [4 q][64 lb][16 col] = 16 KB
    const int tid = threadIdx.x;
    const int lane = tid & 63;
    const int w = tid >> 6;
    const int q = w & 3, j = w >> 2;
    const int blk = blockIdx.x;
    const int grp = blk & 7, nni = blk >> 3;
    const size_t BHs = (size_t)BATCH * H;

    for (int c = 0; c < 8; ++c) {
        int cq = c >> 1, hl = c & 1;
        const u16x8* s8 = (const u16x8*)((hl ? WeL : WeH) + (size_t)((cq * 32 + nni) * KB) * 512);
        u16x8* d8 = (u16x8*)(wlds + c * 8192);
        for (int i = tid; i < 1024; i += NT) d8[i] = s8[i];
    }
    __syncthreads();

    for (int t = 0; t < TSTEPS; ++t) {
        const u16* Ah = hbuf + (size_t)(t & 1) * 2 * BHs;
        const u16* Al = Ah + BHs;
        u16* Hh = hbuf + (size_t)((t + 1) & 1) * 2 * BHs;
        u16* Hl = Hh + BHs;
        f32x4 acc = {};
#pragma unroll 4
        for (int kb = 0; kb < KB; ++kb) {
            bf16x8 bh = *(const bf16x8*)&wlds[((q * 2 + 0) * KB + kb) * 512 + lane * 8];
            bf16x8 bl = *(const bf16x8*)&wlds[((q * 2 + 1) * KB + kb) * 512 + lane * 8];
            size_t ab = ((size_t)((grp * 4 + j) * KB + kb) * 64 + lane) * 8;
            bf16x8 ah = *(const bf16x8*)&Ah[ab];
            bf16x8 al = *(const bf16x8*)&Al[ab];
            acc = MF(ah, bh, acc);
            acc = MF(ah, bl, acc);
            acc = MF(al, bh, acc);
        }
        const int col = lane & 15, rg = lane >> 4;
#pragma unroll
        for (int r = 0; r < 4; ++r)
            exch[(q * 64 + j * 16 + rg * 4 + r) * 16 + col] = acc[r];
        __syncthreads();
        {
            int lb = tid >> 4, cl = tid & 15;
            int b = grp * 64 + lb, n = nni * 16 + cl;
            float x0 = x[((size_t)b * TSTEPS + t) * 2 + 0];
            float x1 = x[((size_t)b * TSTEPS + t) * 2 + 1];
            float g[4];
#pragma unroll
            for (int qq = 0; qq < 4; ++qq)
                g[qq] = exch[(qq * 64 + lb) * 16 + cl] + bc[qq * H + n]
                      + x0 * Wc[(qq * H + n) * 2 + 0] + x1 * Wc[(qq * H + n) * 2 + 1];
            size_t ci = (size_t)b * H + n;
            float cn = sigmoidf_(g[1]) * cbuf[ci] + sigmoidf_(g[0]) * ftanh(g[2]);
            float hn = sigmoidf_(g[3]) * ftanh(cn);
            cbuf[ci] = cn;
            u16 hh = f2bf(hn), hl16 = f2bf(hn - bf2f(hh));
            size_t p = pidx(b, n);
            Hh[p] = hh; Hl[p] = hl16;
            ench[((size_t)b * TSTEPS + t) * H + n] = hh;   // batch-major
        }
        fbar(fE, grp, nni, (unsigned)(t + 1));
    }
}

// ---------------- persistent decoder: 16 waves, 8 groups of 32 blocks ----------------
__global__ __launch_bounds__(NT, 1) void persist_dec(
    const u16* __restrict__ WdiH, const u16* __restrict__ WdiL,
    const u16* __restrict__ WdhH, const u16* __restrict__ WdhL,
    const float* __restrict__ db,
    const u16* __restrict__ WqH, const u16* __restrict__ WqL,
    const u16* __restrict__ u1r, const u16* __restrict__ ench, const float* __restrict__ vv,
    float* __restrict__ cbuf, u16* __restrict__ hbuf,
    u16* __restrict__ dhi, u16* __restrict__ dlo,
    unsigned* __restrict__ fA, unsigned* __restrict__ fC) {
    extern __shared__ char smem[];
    u16* wlds = (u16*)smem;                    // [2 mat][4 q][16 kb][512] hi = 128 KB
    char* scratch = smem + 131072;             // 22 KB overlay region
    float* exch  = (float*)scratch;            // phase A: [4][64][16] = 16 KB
    float* u2row = (float*)scratch;            // phase C: [2][512] = 4 KB
    float* ssc   = (float*)(scratch + 4096);   // [2][100] scores
    float* ssm   = (float*)(scratch + 4928);   // [2][100] softmax
    f32x4* dacc  = (f32x4*)(scratch + 5760);   // [4 slot][2 r][64 l][2] f32x4 = 16 KB
    const int tid = threadIdx.x;
    const int lane = tid & 63;
    const int w = tid >> 6;
    const int blk = blockIdx.x;
    const int grp = blk & 7, nni = blk >> 3;
    const size_t BHs = (size_t)BATCH * H;

    float vvr[8];
    {
        float4 v0 = *(const float4*)&vv[lane * 8];
        float4 v1 = *(const float4*)&vv[lane * 8 + 4];
        vvr[0] = v0.x; vvr[1] = v0.y; vvr[2] = v0.z; vvr[3] = v0.w;
        vvr[4] = v1.x; vvr[5] = v1.y; vvr[6] = v1.z; vvr[7] = v1.w;
    }

    for (int c = 0; c < 8; ++c) {
        int mat = c >> 2, cq = c & 3;
        const u16x8* s8 = (const u16x8*)((mat ? WdhH : WdiH) + (size_t)((cq * 32 + nni) * KB) * 512);
        u16x8* d8 = (u16x8*)(wlds + c * 8192);
        for (int i = tid; i < 1024; i += NT) d8[i] = s8[i];
    }
    __syncthreads();

    for (int s = 0; s < TSTEPS; ++s) {
        // ---- phase A: LSTM gates + cell update; wave = (q, j) ----
        {
            const u16* hAh = hbuf + (size_t)(s & 1) * 2 * BHs;
            const u16* hAl = hAh + BHs;
            u16* Hh = hbuf + (size_t)((s + 1) & 1) * 2 * BHs;
            u16* Hl = Hh + BHs;
            const int q = w & 3, j = w >> 2;
            f32x4 acc = {};
#pragma unroll
            for (int ph = 0; ph < 2; ++ph) {
                const u16* Ah = ph ? hAh : dhi;
                const u16* Al = ph ? hAl : dlo;
                const u16* Wl = ph ? WdhL : WdiL;
#pragma unroll 4
                for (int kb = 0; kb < KB; ++kb) {
                    bf16x8 bh = *(const bf16x8*)&wlds[((ph * 4 + q) * KB + kb) * 512 + lane * 8];
                    bf16x8 bl = *(const bf16x8*)&Wl[((size_t)((q * 32 + nni) * KB + kb) * 64 + lane) * 8];
                    size_t ab = ((size_t)((grp * 4 + j) * KB + kb) * 64 + lane) * 8;
                    bf16x8 ah = *(const bf16x8*)&Ah[ab];
                    bf16x8 al = *(const bf16x8*)&Al[ab];
                    acc = MF(ah, bh, acc);
                    acc = MF(ah, bl, acc);
                    acc = MF(al, bh, acc);
                }
            }
            const int col = lane & 15, rg = lane >> 4;
#pragma unroll
            for (int r = 0; r < 4; ++r)
                exch[(q * 64 + j * 16 + rg * 4 + r) * 16 + col] = acc[r];
            __syncthreads();
            {
                int lb = tid >> 4, cl = tid & 15;
                int b = grp * 64 + lb, n = nni * 16 + cl;
                float g[4];
#pragma unroll
                for (int qq = 0; qq < 4; ++qq)
                    g[qq] = exch[(qq * 64 + lb) * 16 + cl] + db[qq * H + n];
                size_t ci = (size_t)b * H + n;
                float cn = sigmoidf_(g[1]) * cbuf[ci] + sigmoidf_(g[0]) * ftanh(g[2]);
                float hn = sigmoidf_(g[3]) * ftanh(cn);
                cbuf[ci] = cn;
                u16 hh = f2bf(hn), hl16 = f2bf(hn - bf2f(hh));
                size_t p = pidx(b, n);
                Hh[p] = hh; Hl[p] = hl16;
            }
        }
        if (s == TSTEPS - 1) break;
        fbar(fA, grp, nni, (unsigned)(s + 1));

        // ---- phase C: u2 for own 2 rows + attention ----
        {
            const int r = tid >> 9;          // 0..1
            const int par = (tid >> 6) & 7;  // 8 cc-partitions per row
            const int cnt = (par < 4) ? 13 : 12;   // cc = par + 8*i, i < cnt
            const int brow = grp * 64 + 2 * nni + r;
            const u16* u1base = &u1r[(size_t)brow * TSTEPS * H + lane * 8];
            const u16* ehbase = &ench[(size_t)brow * TSTEPS * H + lane * 8];
            // prefetch first 8 ench rows into registers: latency hides under
            // the u2 MFMA + score phase instead of behind the softmax sync
            u16x8 evA[8];
#pragma unroll
            for (int u = 0; u < 8; ++u)
                evA[u] = *(const u16x8*)&ehbase[(size_t)(par + 8 * u) * H];

            {
                const u16* Ah = hbuf + (size_t)((s + 1) & 1) * 2 * BHs;
                const u16* Al = Ah + BHs;
                const int mf = grp * 4 + (nni >> 3);   // m-frag with this block's 2 rows
                f32x4 acc[2] = {};
#pragma unroll 4
                for (int kb = 0; kb < KB; ++kb) {
                    size_t ab = ((size_t)(mf * KB + kb) * 64 + lane) * 8;
                    bf16x8 ah = *(const bf16x8*)&Ah[ab];
                    bf16x8 al = *(const bf16x8*)&Al[ab];
#pragma unroll
                    for (int f = 0; f < 2; ++f) {
                        int n16 = w * 2 + f;
                        size_t fb = ((size_t)(n16 * KB + kb) * 64 + lane) * 8;
                        bf16x8 bh = *(const bf16x8*)&WqH[fb];
                        bf16x8 bl = *(const bf16x8*)&WqL[fb];
                        acc[f] = MF(ah, bh, acc[f]);
                        acc[f] = MF(ah, bl, acc[f]);
                        acc[f] = MF(al, bh, acc[f]);
                    }
                }
                const int col = lane & 15, rg = lane >> 4;
                const int t0 = (nni & 7) * 2;          // rows within the m-frag
#pragma unroll
                for (int f = 0; f < 2; ++f)
#pragma unroll
                    for (int rr = 0; rr < 4; ++rr) {
                        int m = rg * 4 + rr;
                        int n = (w * 2 + f) * 16 + col;
                        if (m == t0)     u2row[n] = acc[f][rr];
                        if (m == t0 + 1) u2row[512 + n] = acc[f][rr];
                    }
            }
            __syncthreads();

            float u2v[8];
            {
                float4 a0 = *(const float4*)&u2row[r * 512 + lane * 8];
                float4 a1 = *(const float4*)&u2row[r * 512 + lane * 8 + 4];
                u2v[0] = a0.x; u2v[1] = a0.y; u2v[2] = a0.z; u2v[3] = a0.w;
                u2v[4] = a1.x; u2v[5] = a1.y; u2v[6] = a1.z; u2v[7] = a1.w;
            }
            // scores: 5-deep load batches, wave-uniform predication
            for (int i0 = 0; i0 < 13; i0 += 5) {
                u16x8 uvv[5];
#pragma unroll
                for (int u = 0; u < 5; ++u) {
                    int i = i0 + u;
                    if (i < cnt)
                        uvv[u] = *(const u16x8*)&u1base[(size_t)(par + 8 * i) * H];
                }
#pragma unroll
                for (int u = 0; u < 5; ++u) {
                    int i = i0 + u;
                    if (i < cnt) {
                        float pp = 0.f;
#pragma unroll
                        for (int jj = 0; jj < 8; ++jj)
                            pp += vvr[jj] * ftanh(bf2f(uvv[u][jj]) + u2v[jj]);
#pragma unroll
                        for (int off = 32; off; off >>= 1) pp += __shfl_xor(pp, off);
                        if (lane == 0) ssc[r * 100 + par + 8 * i] = pp;
                    }
                }
            }
            __syncthreads();
            if (tid < 128) {
                int r2 = tid >> 6, ln = tid & 63;
                float s1 = ssc[r2 * 100 + ln];
                float s2 = (ln + 64 < 100) ? ssc[r2 * 100 + ln + 64] : -1e30f;
                float m = fmaxf(s1, s2);
#pragma unroll
                for (int off = 32; off; off >>= 1) m = fmaxf(m, __shfl_xor(m, off));
                float e1 = __expf(s1 - m);
                float e2 = (ln + 64 < 100) ? __expf(s2 - m) : 0.f;
                float sum = e1 + e2;
#pragma unroll
                for (int off = 32; off; off >>= 1) sum += __shfl_xor(sum, off);
                float inv = 1.f / sum;
                ssm[r2 * 100 + ln] = e1 * inv;
                if (ln + 64 < 100) ssm[r2 * 100 + ln + 64] = e2 * inv;
            }
            __syncthreads();
            // glimpse: first 8 rows already in registers, tail 4-5 loaded now
            float ga[8] = {};
#pragma unroll
            for (int u = 0; u < 8; ++u) {
                float a = ssm[r * 100 + par + 8 * u];
#pragma unroll
                for (int jj = 0; jj < 8; ++jj) ga[jj] += a * bf2f(evA[u][jj]);
            }
            {
                u16x8 evB[5];
#pragma unroll
                for (int u = 0; u < 5; ++u) {
                    int i = 8 + u;
                    if (i < cnt)
                        evB[u] = *(const u16x8*)&ehbase[(size_t)(par + 8 * i) * H];
                }
#pragma unroll
                for (int u = 0; u < 5; ++u) {
                    int i = 8 + u;
                    if (i < cnt) {
                        float a = ssm[r * 100 + par + 8 * i];
#pragma unroll
                        for (int jj = 0; jj < 8; ++jj) ga[jj] += a * bf2f(evB[u][jj]);
                    }
                }
            }
            f32x4 g0 = {ga[0], ga[1], ga[2], ga[3]};
            f32x4 g1 = {ga[4], ga[5], ga[6], ga[7]};
            // deterministic two-round accumulate: slot s holds par=s + par=s+4
            if (par < 4) {
                dacc[(((par * 2 + r) * 64) + lane) * 2 + 0] = g0;
                dacc[(((par * 2 + r) * 64) + lane) * 2 + 1] = g1;
            }
            __syncthreads();
            if (par >= 4) {
                int slot = par - 4;
                f32x4 t0 = dacc[(((slot * 2 + r) * 64) + lane) * 2 + 0];
                f32x4 t1 = dacc[(((slot * 2 + r) * 64) + lane) * 2 + 1];
                dacc[(((slot * 2 + r) * 64) + lane) * 2 + 0] = t0 + g0;
                dacc[(((slot * 2 + r) * 64) + lane) * 2 + 1] = t1 + g1;
            }
            __syncthreads();
            if (tid < 128) {
                int r2 = tid >> 6, l = tid & 63;
                float fin[8];
#pragma unroll
                for (int jj = 0; jj < 8; ++jj) fin[jj] = 0.f;
#pragma unroll
                for (int sl = 0; sl < 4; ++sl) {
                    f32x4 d0 = dacc[(((sl * 2 + r2) * 64) + l) * 2 + 0];
                    f32x4 d1 = dacc[(((sl * 2 + r2) * 64) + l) * 2 + 1];
                    fin[0] += d0[0]; fin[1] += d0[1]; fin[2] += d0[2]; fin[3] += d0[3];
                    fin[4] += d1[0]; fin[5] += d1[1]; fin[6] += d1[2]; fin[7] += d1[3];
                }
                int b2 = grp * 64 + 2 * nni + r2;
                int h0 = l * 8;
#pragma unroll
                for (int qd = 0; qd < 2; ++qd) {
                    int k = h0 + 4 * qd;
                    size_t p = (((size_t)(b2 >> 4) * KB + (k >> 5)) * 64 + (b2 & 15)
                                + (((k >> 2) & 3) << 4)) * 8 + (((k >> 4) & 1) << 2);
                    float f0 = fin[4 * qd], f1 = fin[4 * qd + 1], f2 = fin[4 * qd + 2], f3 = fin[4 * qd + 3];
                    u16 a0 = f2bf(f0), a1 = f2bf(f1), a2 = f2bf(f2), a3 = f2bf(f3);
                    *(ushort4*)&dhi[p] = make_ushort4(a0, a1, a2, a3);
                    u16 c0 = f2bf(f0 - bf2f(a0)), c1 = f2bf(f1 - bf2f(a1));
                    u16 c2 = f2bf(f2 - bf2f(a2)), c3 = f2bf(f3 - bf2f(a3));
                    *(ushort4*)&dlo[p] = make_ushort4(c0, c1, c2, c3);
                }
            }
        }
        fbar(fC, grp, nni, (unsigned)(s + 1));
    }
}

// ---------------- u1 = ench @ W_ref.T (one-shot; rows are b*TSTEPS+cc) ----------------
__global__ __launch_bounds__(256) void gemm_u1(const u16* __restrict__ ench_row,
                                               const u16* __restrict__ Bh, const u16* __restrict__ Bl,
                                               u16* __restrict__ u1_row) {
    __shared__ u16 lds[2 * KB * 64 * 8];   // 32 KB
    const int tid = threadIdx.x;
    const int m0 = blockIdx.x * 32;
    {
        int r = tid >> 3;
        int o = tid & 7;
#pragma unroll
        for (int p8 = 0; p8 < 8; ++p8) {
            int k0 = (o + 8 * p8) * 8;
            const u16* src = &ench_row[(size_t)(m0 + r) * H + k0];
            ushort4 v0 = *(const ushort4*)&src[0];
            ushort4 v1 = *(const ushort4*)&src[4];
            int kb = k0 >> 5, kin0 = k0 & 31;
            int g0 = (kin0 >> 2) & 3;
            int jo = (kin0 >> 4) << 2;
            u16* base = &lds[(size_t)(((r >> 4) * KB + kb) * 64) * 8];
            *(ushort4*)&base[((r & 15) + 16 * g0) * 8 + jo] = v0;
            *(ushort4*)&base[((r & 15) + 16 * (g0 + 1)) * 8 + jo] = v1;
        }
    }
    __syncthreads();
    const int lane = tid & 63;
    const int w = tid >> 6;
    const int mw = w & 1, nh = w >> 1;
    for (int nc = 0; nc < 16; ++nc) {
        int n16 = nh * 16 + nc;
        f32x4 acc = {};
#pragma unroll 4
        for (int kb = 0; kb < KB; ++kb) {
            bf16x8 a = *(const bf16x8*)&lds[((mw * KB + kb) * 64 + lane) * 8];
            size_t fb = ((size_t)(n16 * KB + kb) * 64 + lane) * 8;
            bf16x8 bh = *(const bf16x8*)&Bh[fb];
            bf16x8 bl = *(const bf16x8*)&Bl[fb];
            acc = MF(a, bh, acc);
            acc = MF(a, bl, acc);
        }
        const int col = lane & 15, rg = lane >> 4;
#pragma unroll
        for (int r = 0; r < 4; ++r) {
            size_t mrow = (size_t)m0 + mw * 16 + rg * 4 + r;
            u1_row[mrow * H + n16 * 16 + col] = f2bf(acc[r]);
        }
    }
}

// ---------------- final ----------------
__global__ __launch_bounds__(256) void final_kernel(const u16* __restrict__ hi,
                                                    const u16* __restrict__ lo,
                                                    const float* __restrict__ fc1,
                                                    const float* __restrict__ fc2,
                                                    float* __restrict__ out) {
    const int b = blockIdx.x;
    __shared__ float hsh[H];
    __shared__ float red[256];
    for (int i = threadIdx.x; i < H; i += 256) {
        size_t p = pidx(b, i);
        hsh[i] = bf2f(hi[p]) + bf2f(lo[p]);
    }
    __syncthreads();
    float total = 0.f;
    for (int n = threadIdx.x; n < H; n += 256) {
        float acc = 0.f;
        for (int j = 0; j < H; ++j) acc += fc1[(size_t)n * H + j] * hsh[j];
        total += fmaxf(acc, 0.f) * fc2[n];
    }
    red[threadIdx.x] = total;
    __syncthreads();
    for (int s = 128; s > 0; s >>= 1) {
        if (threadIdx.x < s) red[threadIdx.x] += red[threadIdx.x + s];
        __syncthreads();
    }
    if (threadIdx.x == 0) out[b] = red[0];
}

extern "C" void kernel_launch(void* const* d_in, const int* in_sizes, int n_in,
                              void* d_out, int out_size, void* d_ws, size_t ws_size,
                              hipStream_t stream) {
    (void)in_sizes; (void)n_in; (void)out_size;
    const float* x       = (const float*)d_in[0];
    const float* dec_i1  = (const float*)d_in[1];
    const float* W_emb   = (const float*)d_in[2];
    const float* enc_Wih = (const float*)d_in[3];
    const float* enc_Whh = (const float*)d_in[4];
    const float* enc_bih = (const float*)d_in[5];
    const float* enc_bhh = (const float*)d_in[6];
    const float* dec_Wih = (const float*)d_in[7];
    const float* dec_Whh = (const float*)d_in[8];
    const float* dec_bih = (const float*)d_in[9];
    const float* dec_bhh = (const float*)d_in[10];
    const float* W_q     = (const float*)d_in[11];
    const float* W_ref   = (const float*)d_in[12];
    const float* vv      = (const float*)d_in[13];
    const float* fc1     = (const float*)d_in[14];
    const float* fc2     = (const float*)d_in[15];
    float* out = (float*)d_out;

    const size_t BH = (size_t)BATCH * H;
    const size_t W4 = (size_t)4 * H * H;
    const size_t WS = (size_t)H * H;
    const size_t TBH = (size_t)TSTEPS * BATCH * H;

    unsigned* fA = (unsigned*)d_ws;        // 8*32*16 = 4096 u32 (dec post-LSTM)
    unsigned* fC = fA + 4096;              // 4096 u32 (dec post-attn)
    unsigned* fE = fC + 4096;              // 4096 u32 (enc)
    float* c_  = (float*)(fE + 4096);      // BH
    u16* hbuf  = (u16*)(c_ + BH);          // 4*BH u16: hi0, lo0, hi1, lo1
    float* Wc  = (float*)(hbuf + 4 * BH);  // 4H*2
    float* bc  = Wc + 4 * H * 2;           // 4H
    float* db  = bc + 4 * H;               // 4H
    u16* dhi   = (u16*)(db + 4 * H);       // BH
    u16* dlo   = dhi + BH;                 // BH
    u16* WeH   = dlo + BH;    u16* WeL  = WeH + W4;
    u16* WdiH  = WeL + W4;    u16* WdiL = WdiH + W4;
    u16* WdhH  = WdiL + W4;   u16* WdhL = WdhH + W4;
    u16* WqH   = WdhL + W4;   u16* WqL  = WqH + WS;
    u16* WrH   = WqL + WS;    u16* WrL  = WrH + WS;
    u16* ench  = WrL + WS;                 // TBH batch-major [b][t][h] bf16
    u16* u1r   = ench + TBH;               // TBH batch-major [b][t][h] bf16

    size_t needed = (size_t)((char*)(u1r + TBH) - (char*)d_ws);
    if (ws_size < needed) return;

    const int ENC_SMEM = 131072 + 16384;           // 147456
    const int DEC_SMEM = 131072 + 22528;           // 153600
    (void)hipFuncSetAttribute((const void*)persist_enc, hipFuncAttributeMaxDynamicSharedMemorySize, ENC_SMEM);
    (void)hipFuncSetAttribute((const void*)persist_dec, hipFuncAttributeMaxDynamicSharedMemorySize, DEC_SMEM);

    prep_kernel<<<8, 256, 0, stream>>>(W_emb, enc_Wih, enc_bih, enc_bhh, dec_bih, dec_bhh, Wc, bc, db);
    pack_w<<<(int)(W4 / 256), 256, 0, stream>>>(enc_Whh, WeH, WeL, (int)W4);
    pack_w<<<(int)(W4 / 256), 256, 0, stream>>>(dec_Wih, WdiH, WdiL, (int)W4);
    pack_w<<<(int)(W4 / 256), 256, 0, stream>>>(dec_Whh, WdhH, WdhL, (int)W4);
    pack_w<<<(int)(WS / 256), 256, 0, stream>>>(W_q, WqH, WqL, (int)WS);
    pack_w<<<(int)(WS / 256), 256, 0, stream>>>(W_ref, WrH, WrL, (int)WS);
    pack_w<<<(int)(BH / 256), 256, 0, stream>>>(dec_i1, dhi, dlo, (int)BH);
    // zero: flags(12288 u32) + c(BH) + hbuf(4BH u16 = 2BH f32), contiguous from d_ws
    zero4<<<(int)((12288 + 3 * BH + 255) / 256), 256, 0, stream>>>((float*)d_ws, (int)(12288 + 3 * BH));

    persist_enc<<<NBLK, NT, ENC_SMEM, stream>>>(x, Wc, bc, WeH, WeL, c_, hbuf, ench, fE);
    gemm_u1<<<TSTEPS * BATCH / 32, 256, 0, stream>>>(ench, WrH, WrL, u1r);
    persist_dec<<<NBLK, NT, DEC_SMEM, stream>>>(WdiH, WdiL, WdhH, WdhL, db, WqH, WqL,
                                                u1r, ench, vv, c_, hbuf, dhi, dlo, fA, fC);
    final_kernel<<<BATCH, 256, 0, stream>>>(hbuf, hbuf + BH, fc1, fc2, out);
}